// Round 4
// baseline (206.403 us; speedup 1.0000x reference)
//
#include <hip/hip_runtime.h>
#include <hip/hip_bf16.h>

#define BB 2
#define TT 2048
#define CC 1024
#define HH 16
#define HDD 64

typedef __attribute__((ext_vector_type(8))) short bf16x8;
typedef __attribute__((ext_vector_type(4))) float f32x4;

static __device__ __forceinline__ unsigned short f2bf(float f) {
  union { float f; unsigned u; } v; v.f = f;
  unsigned r = v.u + 0x7fffu + ((v.u >> 16) & 1u);  // RNE
  return (unsigned short)(r >> 16);
}

static __device__ __forceinline__ unsigned fbits(float f) {
  union { float f; unsigned u; } v; v.f = f; return v.u;
}

// pack two fp32 -> two bf16 (truncate) in ONE v_perm_b32
static __device__ __forceinline__ unsigned pk_trunc(float lo, float hi) {
  return __builtin_amdgcn_perm(fbits(hi), fbits(lo), 0x07060302u);
}

// raw v_exp_f32 (args bounded; skips OCML range/subnormal fixup)
static __device__ __forceinline__ float fexp2(float x) {
#if __has_builtin(__builtin_amdgcn_exp2f)
  return __builtin_amdgcn_exp2f(x);
#else
  return exp2f(x);
#endif
}

static __device__ __forceinline__ void gload_lds16(const unsigned short* g, unsigned short* l) {
  __builtin_amdgcn_global_load_lds((const __attribute__((address_space(1))) void*)g,
                                   (__attribute__((address_space(3))) void*)l, 16, 0, 0);
}

// fp32 -> bf16 for x (4M), Wq,Wk,Wv,Wp (1M each), into contiguous dst.
__global__ __launch_bounds__(256) void convert_all(
    const float* __restrict__ x, const float* __restrict__ Wq,
    const float* __restrict__ Wk, const float* __restrict__ Wv,
    const float* __restrict__ Wp, unsigned short* __restrict__ dst)
{
  const size_t M4 = 4194304, M1 = 1048576;
  const size_t e = ((size_t)blockIdx.x * 256 + threadIdx.x) * 8;
  const float* src; size_t off;
  if (e < M4)            { src = x;  off = e; }
  else if (e < M4 + M1)  { src = Wq; off = e - M4; }
  else if (e < M4 + 2*M1){ src = Wk; off = e - M4 - M1; }
  else if (e < M4 + 3*M1){ src = Wv; off = e - M4 - 2*M1; }
  else                   { src = Wp; off = e - M4 - 3*M1; }
  float4 a = *(const float4*)(src + off);
  float4 c = *(const float4*)(src + off + 4);
  unsigned short buf[8] = {f2bf(a.x), f2bf(a.y), f2bf(a.z), f2bf(a.w),
                           f2bf(c.x), f2bf(c.y), f2bf(c.z), f2bf(c.w)};
  *(uint4*)(dst + e) = *(const uint4*)buf;
}

// ---------------------------------------------------------------------------
// R15: 256x256 BK=64 4-phase GEMM, CORRECTED vmcnt ledger (R14 post-mortem).
// R14 failure: halves were contiguous 128-row blocks, so phase reads were
// wave-DEPENDENT (wm=128 waves need A rows 128-191 = "h1" at p0) -> only
// safe wait was a per-tile vmcnt(2) draining a 1-phase-old load (drain0-
// equivalent stall), plus 8 barriers/tile.
// Fix: gload_lds LDS dest is per-WAVE uniform (8 rows/wave) -> halves can be
// NON-CONTIGUOUS row sets chosen so each phase's reads are wave-uniform:
//   h0 = A rows {0-63,128-191}   (lo quadrant of BOTH wave-M groups)
//   h1 = A rows {64-127,192-255}
//   h2 = B rows {0-31,64-95,128-159,192-223} (lo quadrant of all wave-N grps)
//   h3 = B rows {32-63,96-127,160-191,224-255}
// LDS stays LINEAR (logical row = LDS row); ds_reads unchanged; only stage
// address maps change. Stage order h0,h2,h3,h1 == read-first order. FIFO:
//   p0: stage h0(t+1); vmcnt(6) drains h0(t),h2(t)  [issued 4 phases ago]
//   p1: stage h2(t+1); vmcnt(6) drains h3(t)        [4 phases ago]
//   p2: stage h3(t+1); vmcnt(6) drains h1(t)        [4 phases ago]
//   p3: stage h1(t+1); no wait (all-register phase)
// 3 barriers per K-tile (p0/p1/p2 starts). Tail tile: vmcnt(4)/(2)/(0).
// Never drains a load younger than 4 phases (T4 proper). Swizzle unchanged
// (proven: conflicts 0). grid (16,12), 512 thr, LDS 128 KB, 1 block/CU.
// ---------------------------------------------------------------------------
__global__ __launch_bounds__(512, 2) void gemm_mfma(
    const unsigned short* __restrict__ A, const unsigned short* __restrict__ W,
    const float* __restrict__ b0, const float* __restrict__ b1, const float* __restrict__ b2,
    unsigned short* __restrict__ oQ, unsigned short* __restrict__ oK,
    unsigned short* __restrict__ oVt)
{
  __shared__ unsigned short As[2][256][64];
  __shared__ unsigned short Bs[2][256][64];
  const int t = threadIdx.x;
  const int wv = __builtin_amdgcn_readfirstlane(t >> 6);  // 0..7
  const int ln = t & 63;
  const int l16 = ln & 15;
  const int quad = ln >> 4;
  const int mBase = blockIdx.x * 256;
  const int nBase = blockIdx.y * 256;
  const int wm = (wv >> 2) * 128;   // {0,128}
  const int wn = (wv & 3) * 64;     // {0,64,128,192}

  f32x4 acc[8][4];
#pragma unroll
  for (int i = 0; i < 8; i++)
#pragma unroll
    for (int j = 0; j < 4; j++) acc[i][j] = (f32x4){0.f, 0.f, 0.f, 0.f};

  // stage maps. srow = t>>3 (0..63); chunk t&7 holds logical chunk
  // (t&7)^(row&7) (all row offsets are ==0 mod 8, so swizzle key = srow&7).
  const int srow = t >> 3;
  const int schunk = ((t & 7) ^ (srow & 7)) * 8;
  const int rB = srow + ((t >> 8) << 5);     // waves0-3: 0..31; waves4-7: 64..95
  const unsigned short* gA = A + (size_t)(mBase + srow) * CC + schunk;
  const unsigned short* gB = W + (size_t)(nBase + rB) * CC + schunk;

  // ds_read swizzle (row&7 == l16&7 for all read rows)
  const int sw0 = ((0 + quad) ^ (l16 & 7)) * 8;
  const int sw1 = ((4 + quad) ^ (l16 & 7)) * 8;

  // A half: issue1 rows {0..63}+64*half, issue2 = issue1+128. 2 loads.
#define STAGE_A(bi, kt, half)                                                   \
  do {                                                                          \
    const unsigned short* s_ = gA + (size_t)((half) * 64) * CC + (size_t)(kt) * 64; \
    unsigned short* d_ = &As[bi][0][0] + t * 8 + (half) * 4096;                 \
    gload_lds16(s_, d_);                                                        \
    gload_lds16(s_ + (size_t)128 * CC, d_ + 8192);                              \
  } while (0)
  // B half: issue1 rows {0..31,64..95}+32*half, issue2 = issue1+128. 2 loads.
#define STAGE_B(bi, kt, half)                                                   \
  do {                                                                          \
    const unsigned short* s_ = gB + (size_t)((half) * 32) * CC + (size_t)(kt) * 64; \
    unsigned short* d_ = &Bs[bi][0][0] + t * 8 + ((t >> 8) << 11) + (half) * 2048; \
    gload_lds16(s_, d_);                                                        \
    gload_lds16(s_ + (size_t)128 * CC, d_ + 8192);                              \
  } while (0)

  // prologue: tile 0, stage order h0,h2,h3,h1 (FIFO aligned with reads)
  STAGE_A(0, 0, 0);   // h0
  STAGE_B(0, 0, 0);   // h2
  STAGE_B(0, 0, 1);   // h3
  STAGE_A(0, 0, 1);   // h1

  bf16x8 af[4][2], bfr[4][2];
  for (int kt = 0; kt < 16; ++kt) {
    const int buf = kt & 1, nb = buf ^ 1;

    // ---- p0: stage h0(t+1); wait h0(t),h2(t); read A-lo + B-lo; MFMA q00
    if (kt < 15) {
      STAGE_A(nb, kt + 1, 0);
      asm volatile("s_waitcnt vmcnt(6)" ::: "memory");
    } else {
      asm volatile("s_waitcnt vmcnt(4)" ::: "memory");
    }
    __builtin_amdgcn_s_barrier();
    asm volatile("" ::: "memory");
#pragma unroll
    for (int i = 0; i < 4; ++i) {
      af[i][0] = *(const bf16x8*)&As[buf][wm + i * 16 + l16][sw0];
      af[i][1] = *(const bf16x8*)&As[buf][wm + i * 16 + l16][sw1];
    }
#pragma unroll
    for (int j = 0; j < 2; ++j) {
      bfr[j][0] = *(const bf16x8*)&Bs[buf][wn + j * 16 + l16][sw0];
      bfr[j][1] = *(const bf16x8*)&Bs[buf][wn + j * 16 + l16][sw1];
    }
    __builtin_amdgcn_s_setprio(1);
#pragma unroll
    for (int i = 0; i < 4; ++i)
#pragma unroll
      for (int j = 0; j < 2; ++j) {
        acc[i][j] = __builtin_amdgcn_mfma_f32_16x16x32_bf16(af[i][0], bfr[j][0], acc[i][j], 0, 0, 0);
        acc[i][j] = __builtin_amdgcn_mfma_f32_16x16x32_bf16(af[i][1], bfr[j][1], acc[i][j], 0, 0, 0);
      }
    __builtin_amdgcn_s_setprio(0);
    asm volatile("" ::: "memory");

    // ---- p1: stage h2(t+1); wait h3(t); read B-hi; MFMA q01
    if (kt < 15) {
      STAGE_B(nb, kt + 1, 0);
      asm volatile("s_waitcnt vmcnt(6)" ::: "memory");
    } else {
      asm volatile("s_waitcnt vmcnt(2)" ::: "memory");
    }
    __builtin_amdgcn_s_barrier();
    asm volatile("" ::: "memory");
#pragma unroll
    for (int j = 2; j < 4; ++j) {
      bfr[j][0] = *(const bf16x8*)&Bs[buf][wn + j * 16 + l16][sw0];
      bfr[j][1] = *(const bf16x8*)&Bs[buf][wn + j * 16 + l16][sw1];
    }
    __builtin_amdgcn_s_setprio(1);
#pragma unroll
    for (int i = 0; i < 4; ++i)
#pragma unroll
      for (int j = 2; j < 4; ++j) {
        acc[i][j] = __builtin_amdgcn_mfma_f32_16x16x32_bf16(af[i][0], bfr[j][0], acc[i][j], 0, 0, 0);
        acc[i][j] = __builtin_amdgcn_mfma_f32_16x16x32_bf16(af[i][1], bfr[j][1], acc[i][j], 0, 0, 0);
      }
    __builtin_amdgcn_s_setprio(0);
    asm volatile("" ::: "memory");

    // ---- p2: stage h3(t+1); wait h1(t); read A-hi; MFMA q10
    if (kt < 15) {
      STAGE_B(nb, kt + 1, 1);
      asm volatile("s_waitcnt vmcnt(6)" ::: "memory");
    } else {
      asm volatile("s_waitcnt vmcnt(0)" ::: "memory");
    }
    __builtin_amdgcn_s_barrier();
    asm volatile("" ::: "memory");
#pragma unroll
    for (int i = 0; i < 4; ++i) {
      af[i][0] = *(const bf16x8*)&As[buf][wm + 64 + i * 16 + l16][sw0];
      af[i][1] = *(const bf16x8*)&As[buf][wm + 64 + i * 16 + l16][sw1];
    }
    __builtin_amdgcn_s_setprio(1);
#pragma unroll
    for (int i = 0; i < 4; ++i)
#pragma unroll
      for (int j = 0; j < 2; ++j) {
        acc[4 + i][j] = __builtin_amdgcn_mfma_f32_16x16x32_bf16(af[i][0], bfr[j][0], acc[4 + i][j], 0, 0, 0);
        acc[4 + i][j] = __builtin_amdgcn_mfma_f32_16x16x32_bf16(af[i][1], bfr[j][1], acc[4 + i][j], 0, 0, 0);
      }
    __builtin_amdgcn_s_setprio(0);
    asm volatile("" ::: "memory");

    // ---- p3: stage h1(t+1); no wait, no barrier (all-register); MFMA q11
    if (kt < 15) STAGE_A(nb, kt + 1, 1);
    __builtin_amdgcn_s_setprio(1);
#pragma unroll
    for (int i = 0; i < 4; ++i)
#pragma unroll
      for (int j = 2; j < 4; ++j) {
        acc[4 + i][j] = __builtin_amdgcn_mfma_f32_16x16x32_bf16(af[i][0], bfr[j][0], acc[4 + i][j], 0, 0, 0);
        acc[4 + i][j] = __builtin_amdgcn_mfma_f32_16x16x32_bf16(af[i][1], bfr[j][1], acc[4 + i][j], 0, 0, 0);
      }
    __builtin_amdgcn_s_setprio(0);
    asm volatile("" ::: "memory");
  }
#undef STAGE_A
#undef STAGE_B

  const int which = nBase >> 10;
  const float* bias = which == 0 ? b0 : (which == 1 ? b1 : b2);
  unsigned short* dst = which == 0 ? oQ : (which == 1 ? oK : oVt);
  const float scl = which == 0 ? 0.1803368801f : 1.0f;  // 0.125*log2(e) on Q
#pragma unroll
  for (int i = 0; i < 8; i++)
#pragma unroll
    for (int r = 0; r < 4; r++) {
      const int m = mBase + wm + i * 16 + quad * 4 + r;
      const int b = m >> 11, tp = m & 2047;
#pragma unroll
      for (int j = 0; j < 4; j++) {
        const int n = nBase + wn + j * 16 + l16;
        const int nl = n & 1023, h = nl >> 6, d = nl & 63;
        const unsigned short v = f2bf((acc[i][j][r] + bias[nl]) * scl);
        if (which < 2) dst[((size_t)(b * HH + h) * TT + tp) * HDD + d] = v;
        else           dst[((size_t)(b * HH + h) * HDD + d) * TT + tp] = v;
      }
    }
}

// Output projection: 128x128 tile, BK=32 dbuf, counted vmcnt, 512 threads,
// grid (32,8) = 256 blocks (unchanged from R13).
__global__ __launch_bounds__(512) void gemm_proj(
    const unsigned short* __restrict__ A, const unsigned short* __restrict__ W,
    const float* __restrict__ bias, float* __restrict__ out)
{
  __shared__ unsigned short As[2][128][32];
  __shared__ unsigned short Bs[2][128][32];
  const int t = threadIdx.x;
  const int wv = __builtin_amdgcn_readfirstlane(t >> 6);  // 0..7
  const int ln = t & 63;
  const int l16 = ln & 15;
  const int quad = ln >> 4;
  const int mBase = blockIdx.x * 128;
  const int nBase = blockIdx.y * 128;
  const int wm = (wv >> 2) * 64;        // {0,64}
  const int wn = (wv & 3) * 32;         // {0,32,64,96}

  f32x4 acc[4][2];
#pragma unroll
  for (int i = 0; i < 4; i++)
#pragma unroll
    for (int j = 0; j < 2; j++) acc[i][j] = (f32x4){0.f, 0.f, 0.f, 0.f};

  const int rloc = t >> 2;                               // 0..127
  const int csrc = ((t & 3) ^ ((t >> 3) & 3)) * 8;
  const unsigned short* gA = A + (size_t)(mBase + rloc) * CC + csrc;
  const unsigned short* gB = W + (size_t)(nBase + rloc) * CC + csrc;
  const int sw = (quad ^ ((l16 >> 1) & 3)) * 8;

#define STAGE(b, kt)                                                       \
  do {                                                                     \
    const size_t ko = (size_t)(kt) * 32;                                   \
    gload_lds16(gA + ko, &As[b][0][0] + t * 8);                            \
    gload_lds16(gB + ko, &Bs[b][0][0] + t * 8);                            \
  } while (0)

  STAGE(0, 0);
  for (int kt = 0; kt < 32; ++kt) {
    const int cur = kt & 1;
    if (kt < 31) {
      STAGE(cur ^ 1, kt + 1);
      asm volatile("s_waitcnt vmcnt(2)" ::: "memory");
    } else {
      asm volatile("s_waitcnt vmcnt(0)" ::: "memory");
    }
    __builtin_amdgcn_s_barrier();
    asm volatile("" ::: "memory");
    bf16x8 af[4], bfr[2];
#pragma unroll
    for (int i = 0; i < 4; ++i) af[i] = *(const bf16x8*)&As[cur][wm + i * 16 + l16][sw];
#pragma unroll
    for (int j = 0; j < 2; ++j) bfr[j] = *(const bf16x8*)&Bs[cur][wn + j * 16 + l16][sw];
    __builtin_amdgcn_s_setprio(1);
#pragma unroll
    for (int i = 0; i < 4; ++i)
#pragma unroll
      for (int j = 0; j < 2; ++j)
        acc[i][j] = __builtin_amdgcn_mfma_f32_16x16x32_bf16(af[i], bfr[j], acc[i][j], 0, 0, 0);
    __builtin_amdgcn_s_setprio(0);
    asm volatile("" ::: "memory");
    __builtin_amdgcn_s_barrier();
    asm volatile("" ::: "memory");
  }
#undef STAGE

#pragma unroll
  for (int i = 0; i < 4; i++)
#pragma unroll
    for (int r = 0; r < 4; r++) {
      const int m = mBase + wm + i * 16 + quad * 4 + r;
#pragma unroll
      for (int j = 0; j < 2; j++) {
        const int n = nBase + wn + j * 16 + l16;
        out[(size_t)m * CC + n] = acc[i][j][r] + bias[n];
      }
    }
}

// MFMA bf16 flash attention — R7 paired structure (unchanged this round).
__global__ __launch_bounds__(256, 2) void attn_mfma(
    const unsigned short* __restrict__ Q, const unsigned short* __restrict__ K,
    const unsigned short* __restrict__ Vt, unsigned short* __restrict__ y)
{
  __shared__ unsigned short QP[128][72];      // Q tiles; becomes P after qfrag extract
  __shared__ unsigned short Ks[2][64][72];
  __shared__ unsigned short Vts[2][64][72];

  const int t = threadIdx.x;
  const int a = blockIdx.x;        // 0..15
  const int bh = blockIdx.y;       // 0..31
  const int wave = t >> 6;
  const int lane = t & 63;
  const int l16 = lane & 15;
  const int quad = lane >> 4;

  const size_t base = (size_t)bh * TT * HDD;
  const int qtL = a, qtH = 31 - a;
  const int qBaseL = qtL * 64, qBaseH = qtH * 64;

  // stage Q: rows 0..63 = lo tile, 64..127 = hi tile
#pragma unroll
  for (int p = 0; p < 4; p++) {
    const int c = p * 256 + t;
    const int r = c >> 3, off = (c & 7) * 8;
    const int srcRow = (r < 64) ? (qBaseL + r) : (qBaseH + r - 64);
    *(uint4*)&QP[r][off] = *(const uint4*)(Q + base + (size_t)srcRow * HDD + off);
  }

  // K/V register prefetch (tile 0)
  const int sr = t >> 2, sc = (t & 3) * 8;
  const unsigned short* kbase = K + base + (size_t)sr * HDD + sc;
  const unsigned short* vbase = Vt + base + (size_t)sr * TT + sc;
  uint4 kr0 = *(const uint4*)(kbase);
  uint4 kr1 = *(const uint4*)(kbase + 32);
  uint4 vr0 = *(const uint4*)(vbase);
  uint4 vr1 = *(const uint4*)(vbase + 32);
  __syncthreads();  // Q staged

  bf16x8 qfL0 = *(const bf16x8*)&QP[wave * 16 + l16][quad * 8];
  bf16x8 qfL1 = *(const bf16x8*)&QP[wave * 16 + l16][32 + quad * 8];
  bf16x8 qfH0 = *(const bf16x8*)&QP[64 + wave * 16 + l16][quad * 8];
  bf16x8 qfH1 = *(const bf16x8*)&QP[64 + wave * 16 + l16][32 + quad * 8];
  unsigned short (*PtH)[72] = (unsigned short (*)[72])&QP[wave * 16];
  unsigned short (*PtL)[72] = (unsigned short (*)[72])&QP[64 + wave * 16];

  float lL = 0.f, lH = 0.f;  // per-lane partial; cross-quad reduce deferred
  f32x4 OfrL[4], OfrH[4];
#pragma unroll
  for (int dt = 0; dt < 4; dt++) {
    OfrL[dt] = (f32x4){0.f, 0.f, 0.f, 0.f};
    OfrH[dt] = (f32x4){0.f, 0.f, 0.f, 0.f};
  }

  for (int kt = 0; kt <= qtH; kt++) {
    const int buf = kt & 1;
    *(uint4*)&Ks[buf][sr][sc]       = kr0;
    *(uint4*)&Ks[buf][sr][sc + 32]  = kr1;
    *(uint4*)&Vts[buf][sr][sc]      = vr0;
    *(uint4*)&Vts[buf][sr][sc + 32] = vr1;
    __syncthreads();  // ONLY barrier: commits visible; prior-buf readers done
    if (kt < qtH) {
      kr0 = *(const uint4*)(kbase + (size_t)(kt + 1) * 64 * HDD);
      kr1 = *(const uint4*)(kbase + (size_t)(kt + 1) * 64 * HDD + 32);
      vr0 = *(const uint4*)(vbase + (kt + 1) * 64);
      vr1 = *(const uint4*)(vbase + (kt + 1) * 64 + 32);
    }
    const bool doLo = (kt <= qtL);

    // S^T = K Q^T
    f32x4 StH[4], StL[4];
#pragma unroll
    for (int ct = 0; ct < 4; ct++) {
      bf16x8 a0 = *(const bf16x8*)&Ks[buf][ct * 16 + l16][quad * 8];
      bf16x8 a1 = *(const bf16x8*)&Ks[buf][ct * 16 + l16][32 + quad * 8];
      f32x4 s = (f32x4){0.f, 0.f, 0.f, 0.f};
      s = __builtin_amdgcn_mfma_f32_16x16x32_bf16(a0, qfH0, s, 0, 0, 0);
      s = __builtin_amdgcn_mfma_f32_16x16x32_bf16(a1, qfH1, s, 0, 0, 0);
      StH[ct] = s;
      if (doLo) {
        f32x4 s2 = (f32x4){0.f, 0.f, 0.f, 0.f};
        s2 = __builtin_amdgcn_mfma_f32_16x16x32_bf16(a0, qfL0, s2, 0, 0, 0);
        s2 = __builtin_amdgcn_mfma_f32_16x16x32_bf16(a1, qfL1, s2, 0, 0, 0);
        StL[ct] = s2;
      }
    }

    // softmax hi (mask only on the diagonal iteration — wave-uniform branch)
    if (kt == qtH) {
#pragma unroll
      for (int ct = 0; ct < 4; ct++) {
        float p[4];
#pragma unroll
        for (int r = 0; r < 4; r++) {
          float pv = fexp2(StH[ct][r]);
          if (ct * 16 + quad * 4 + r > wave * 16 + l16) pv = 0.f;
          p[r] = pv;
        }
        lH += (p[0] + p[1]) + (p[2] + p[3]);
        uint2 pk = {pk_trunc(p[0], p[1]), pk_trunc(p[2], p[3])};
        *(uint2*)&PtH[l16][ct * 16 + quad * 4] = pk;
      }
    } else {
#pragma unroll
      for (int ct = 0; ct < 4; ct++) {
        float p[4];
#pragma unroll
        for (int r = 0; r < 4; r++) p[r] = fexp2(StH[ct][r]);
        lH += (p[0] + p[1]) + (p[2] + p[3]);
        uint2 pk = {pk_trunc(p[0], p[1]), pk_trunc(p[2], p[3])};
        *(uint2*)&PtH[l16][ct * 16 + quad * 4] = pk;
      }
    }
    if (doLo) {
      if (kt == qtL) {
#pragma unroll
        for (int ct = 0; ct < 4; ct++) {
          float p[4];
#pragma unroll
          for (int r = 0; r < 4; r++) {
            float pv = fexp2(StL[ct][r]);
            if (ct * 16 + quad * 4 + r > wave * 16 + l16) pv = 0.f;
            p[r] = pv;
          }
          lL += (p[0] + p[1]) + (p[2] + p[3]);
          uint2 pk = {pk_trunc(p[0], p[1]), pk_trunc(p[2], p[3])};
          *(uint2*)&PtL[l16][ct * 16 + quad * 4] = pk;
        }
      } else {
#pragma unroll
        for (int ct = 0; ct < 4; ct++) {
          float p[4];
#pragma unroll
          for (int r = 0; r < 4; r++) p[r] = fexp2(StL[ct][r]);
          lL += (p[0] + p[1]) + (p[2] + p[3]);
          uint2 pk = {pk_trunc(p[0], p[1]), pk_trunc(p[2], p[3])};
          *(uint2*)&PtL[l16][ct * 16 + quad * 4] = pk;
        }
      }
    }

    // O += P V (Pt wave-private: in-wave lgkmcnt ordering, no barrier)
    bf16x8 paH0 = *(const bf16x8*)&PtH[l16][quad * 8];
    bf16x8 paH1 = *(const bf16x8*)&PtH[l16][32 + quad * 8];
    bf16x8 paL0, paL1;
    if (doLo) {
      paL0 = *(const bf16x8*)&PtL[l16][quad * 8];
      paL1 = *(const bf16x8*)&PtL[l16][32 + quad * 8];
    }
#pragma unroll
    for (int dt = 0; dt < 4; dt++) {
      bf16x8 vb0 = *(const bf16x8*)&Vts[buf][dt * 16 + l16][quad * 8];
      bf16x8 vb1 = *(const bf16x8*)&Vts[buf][dt * 16 + l16][32 + quad * 8];
      OfrH[dt] = __builtin_amdgcn_mfma_f32_16x16x32_bf16(paH0, vb0, OfrH[dt], 0, 0, 0);
      OfrH[dt] = __builtin_amdgcn_mfma_f32_16x16x32_bf16(paH1, vb1, OfrH[dt], 0, 0, 0);
      if (doLo) {
        OfrL[dt] = __builtin_amdgcn_mfma_f32_16x16x32_bf16(paL0, vb0, OfrL[dt], 0, 0, 0);
        OfrL[dt] = __builtin_amdgcn_mfma_f32_16x16x32_bf16(paL1, vb1, OfrL[dt], 0, 0, 0);
      }
    }
    // no trailing barrier: next iter commits the OTHER buffer
  }

  // deferred cross-quad l reduction
  lL += __shfl_xor(lL, 16, 64); lL += __shfl_xor(lL, 32, 64);
  lH += __shfl_xor(lH, 16, 64); lH += __shfl_xor(lH, 32, 64);

  const int b = bh >> 4, h = bh & 15;
  float lRowL[4], lRowH[4];
#pragma unroll
  for (int r = 0; r < 4; r++) {
    lRowL[r] = __shfl(lL, quad * 4 + r, 16);
    lRowH[r] = __shfl(lH, quad * 4 + r, 16);
  }
#pragma unroll
  for (int r = 0; r < 4; r++) {
    const int qL = qBaseL + wave * 16 + quad * 4 + r;
    const int qH = qBaseH + wave * 16 + quad * 4 + r;
    const float invL = 1.0f / lRowL[r];
    const float invH = 1.0f / lRowH[r];
    unsigned short* ypL = y + ((size_t)(b * TT + qL)) * CC + h * 64 + l16;
    unsigned short* ypH = y + ((size_t)(b * TT + qH)) * CC + h * 64 + l16;
#pragma unroll
    for (int dt = 0; dt < 4; dt++) {
      ypL[dt * 16] = f2bf(OfrL[dt][r] * invL);
      ypH[dt * 16] = f2bf(OfrH[dt][r] * invH);
    }
  }
}

extern "C" void kernel_launch(void* const* d_in, const int* in_sizes, int n_in,
                              void* d_out, int out_size, void* d_ws, size_t ws_size,
                              hipStream_t stream) {
  const float* x  = (const float*)d_in[0];
  const float* Wq = (const float*)d_in[1];
  const float* bq = (const float*)d_in[2];
  const float* Wk = (const float*)d_in[3];
  const float* bk = (const float*)d_in[4];
  const float* Wv = (const float*)d_in[5];
  const float* bv = (const float*)d_in[6];
  const float* Wp = (const float*)d_in[7];
  const float* bp = (const float*)d_in[8];

  const size_t M4 = 4194304, M1 = 1048576;
  unsigned short* xb   = (unsigned short*)d_ws;  // 4M
  unsigned short* wqb  = xb + M4;                // wq,wk,wv,wp contiguous
  unsigned short* wpb  = wqb + 3 * M1;
  unsigned short* wsQ  = wpb + M1;               // [B,H,T,HD] (pre-scaled)
  unsigned short* wsK  = wsQ + M4;               // [B,H,T,HD]
  unsigned short* wsVt = wsK + M4;               // [B,H,HD,T]
  unsigned short* yb   = wsVt + M4;              // [B,T,C] bf16

  convert_all<<<4096, 256, 0, stream>>>(x, Wq, Wk, Wv, Wp, xb);
  gemm_mfma<<<dim3(16, 12), 512, 0, stream>>>(xb, wqb, bq, bk, bv,
                                              wsQ, wsK, wsVt);
  attn_mfma<<<dim3(16, BB * HH), 256, 0, stream>>>(wsQ, wsK, wsVt, yb);
  gemm_proj<<<dim3(32, 8), 512, 0, stream>>>(yb, wpb, bp, (float*)d_out);
}

// Round 5
// 203.562 us; speedup vs baseline: 1.0140x; 1.0140x over previous
//
#include <hip/hip_runtime.h>
#include <hip/hip_bf16.h>

#define BB 2
#define TT 2048
#define CC 1024
#define HH 16
#define HDD 64

typedef __attribute__((ext_vector_type(8))) short bf16x8;
typedef __attribute__((ext_vector_type(4))) float f32x4;

static __device__ __forceinline__ unsigned short f2bf(float f) {
  union { float f; unsigned u; } v; v.f = f;
  unsigned r = v.u + 0x7fffu + ((v.u >> 16) & 1u);  // RNE
  return (unsigned short)(r >> 16);
}

static __device__ __forceinline__ unsigned fbits(float f) {
  union { float f; unsigned u; } v; v.f = f; return v.u;
}

// pack two fp32 -> two bf16 (truncate) in ONE v_perm_b32
static __device__ __forceinline__ unsigned pk_trunc(float lo, float hi) {
  return __builtin_amdgcn_perm(fbits(hi), fbits(lo), 0x07060302u);
}

// raw v_exp_f32 (args bounded; skips OCML range/subnormal fixup)
static __device__ __forceinline__ float fexp2(float x) {
#if __has_builtin(__builtin_amdgcn_exp2f)
  return __builtin_amdgcn_exp2f(x);
#else
  return exp2f(x);
#endif
}

static __device__ __forceinline__ void gload_lds16(const unsigned short* g, unsigned short* l) {
  __builtin_amdgcn_global_load_lds((const __attribute__((address_space(1))) void*)g,
                                   (__attribute__((address_space(3))) void*)l, 16, 0, 0);
}

// fp32 -> bf16 for x (4M), Wq,Wk,Wv,Wp (1M each), into contiguous dst.
__global__ __launch_bounds__(256) void convert_all(
    const float* __restrict__ x, const float* __restrict__ Wq,
    const float* __restrict__ Wk, const float* __restrict__ Wv,
    const float* __restrict__ Wp, unsigned short* __restrict__ dst)
{
  const size_t M4 = 4194304, M1 = 1048576;
  const size_t e = ((size_t)blockIdx.x * 256 + threadIdx.x) * 8;
  const float* src; size_t off;
  if (e < M4)            { src = x;  off = e; }
  else if (e < M4 + M1)  { src = Wq; off = e - M4; }
  else if (e < M4 + 2*M1){ src = Wk; off = e - M4 - M1; }
  else if (e < M4 + 3*M1){ src = Wv; off = e - M4 - 2*M1; }
  else                   { src = Wp; off = e - M4 - 3*M1; }
  float4 a = *(const float4*)(src + off);
  float4 c = *(const float4*)(src + off + 4);
  unsigned short buf[8] = {f2bf(a.x), f2bf(a.y), f2bf(a.z), f2bf(a.w),
                           f2bf(c.x), f2bf(c.y), f2bf(c.z), f2bf(c.w)};
  *(uint4*)(dst + e) = *(const uint4*)buf;
}

// ---------------------------------------------------------------------------
// R16: m201-FAITHFUL 8-phase 256x256 BK=64 GEMM.
// R15 discrepancy found: reads were issued AFTER the phase barrier and
// consumed immediately -> full LDS latency exposed as lockstep stall every
// phase. m201's phase = {ds_read quadrant || stage 1 half || BAR || lgkm ||
// 16 MFMA || BAR}: reads progress during barrier-arrival skew, and the
// 2-barrier discipline is what the learn loop verified (m201: 62% MfmaUtil).
// Halves (union over waves of one quadrant's operand rows):
//   hA0 = A rows {0-63,128-191}, hA1 = {64-127,192-255}
//   hB0 = B rows {0-31,64-95,128-159,192-223}, hB1 = +32
// Last-read phase (per K-tile): hA0:q00, hB0:q00, hB1:q01, hA1:q10.
// Iteration = 2 K-tiles (T0=2it buf0, T1=2it+1 buf1), phases 1-8:
//   ph1 q00(T0): stage hA1(T1)    ph5 q00(T1): stage hA1(T0+2)
//   ph2 q01(T0): stage hA0(T0+2)  ph6 q01(T1): stage hA0(T1+2)
//   ph3 q10(T0): stage hB0(T0+2)  ph7 q10(T1): stage hB0(T1+2)
//   ph4 q11(T0): stage hB1(T0+2), vmcnt(6)
//   ph8 q11(T1): stage hB1(T1+2), vmcnt(6)
// Every stage lands >=1 barrier after its half's last reader (WAR ok); every
// half is drained by a vmcnt(6) issued >=4 phases after its stage (RAW ok).
// Prologue: 7 halves staged, vmcnt(6) drains tile0. Tail it=7: stage guards
// off (except ph1's hA1(15)), ph4 uses vmcnt(0).
// Stage macros / swizzle / epilogue identical to R15 (numerically verified).
// ---------------------------------------------------------------------------
__global__ __launch_bounds__(512, 2) void gemm_mfma(
    const unsigned short* __restrict__ A, const unsigned short* __restrict__ W,
    const float* __restrict__ b0, const float* __restrict__ b1, const float* __restrict__ b2,
    unsigned short* __restrict__ oQ, unsigned short* __restrict__ oK,
    unsigned short* __restrict__ oVt)
{
  __shared__ unsigned short As[2][256][64];
  __shared__ unsigned short Bs[2][256][64];
  const int t = threadIdx.x;
  const int wv = __builtin_amdgcn_readfirstlane(t >> 6);  // 0..7
  const int ln = t & 63;
  const int l16 = ln & 15;
  const int quad = ln >> 4;
  const int mBase = blockIdx.x * 256;
  const int nBase = blockIdx.y * 256;
  const int wm = (wv >> 2) * 128;   // {0,128}
  const int wn = (wv & 3) * 64;     // {0,64,128,192}

  f32x4 acc[8][4];
#pragma unroll
  for (int i = 0; i < 8; i++)
#pragma unroll
    for (int j = 0; j < 4; j++) acc[i][j] = (f32x4){0.f, 0.f, 0.f, 0.f};

  const int srow = t >> 3;                        // 0..63
  const int schunk = ((t & 7) ^ (srow & 7)) * 8;  // pre-swizzled source chunk
  const int rB0 = srow + ((t >> 8) << 5);         // B row map (group split)
  const unsigned short* gA = A + (size_t)(mBase + srow) * CC + schunk;
  const unsigned short* gB = W + (size_t)(nBase + rB0) * CC + schunk;

  const int sw0 = ((0 + quad) ^ (l16 & 7)) * 8;
  const int sw1 = ((4 + quad) ^ (l16 & 7)) * 8;

#define STAGE_A(bi, kt, half)                                                   \
  do {                                                                          \
    const unsigned short* s_ = gA + (size_t)((half) * 64) * CC + (size_t)(kt) * 64; \
    unsigned short* d_ = &As[bi][0][0] + t * 8 + (half) * 4096;                 \
    gload_lds16(s_, d_);                                                        \
    gload_lds16(s_ + (size_t)128 * CC, d_ + 8192);                              \
  } while (0)
#define STAGE_B(bi, kt, half)                                                   \
  do {                                                                          \
    const unsigned short* s_ = gB + (size_t)((half) * 32) * CC + (size_t)(kt) * 64; \
    unsigned short* d_ = &Bs[bi][0][0] + t * 8 + ((t >> 8) << 11) + (half) * 2048; \
    gload_lds16(s_, d_);                                                        \
    gload_lds16(s_ + (size_t)128 * CC, d_ + 8192);                              \
  } while (0)

#define PBAR()                                                                  \
  do {                                                                          \
    asm volatile("" ::: "memory");                                              \
    __builtin_amdgcn_s_barrier();                                               \
    asm volatile("" ::: "memory");                                              \
  } while (0)

#define RD_A(bufc, rbase)                                                       \
  do {                                                                          \
    _Pragma("unroll")                                                           \
    for (int i_ = 0; i_ < 4; ++i_) {                                            \
      af[i_][0] = *(const bf16x8*)&As[bufc][(rbase) + i_ * 16 + l16][sw0];      \
      af[i_][1] = *(const bf16x8*)&As[bufc][(rbase) + i_ * 16 + l16][sw1];      \
    }                                                                           \
  } while (0)
#define RD_B(bufc, jb)                                                          \
  do {                                                                          \
    _Pragma("unroll")                                                           \
    for (int j_ = 0; j_ < 2; ++j_) {                                            \
      bfr[(jb) + j_][0] = *(const bf16x8*)&Bs[bufc][wn + ((jb) + j_) * 16 + l16][sw0]; \
      bfr[(jb) + j_][1] = *(const bf16x8*)&Bs[bufc][wn + ((jb) + j_) * 16 + l16][sw1]; \
    }                                                                           \
  } while (0)

#define MFQ(ib, jb)                                                             \
  do {                                                                          \
    __builtin_amdgcn_s_setprio(1);                                              \
    _Pragma("unroll")                                                           \
    for (int i_ = 0; i_ < 4; ++i_) {                                            \
      _Pragma("unroll")                                                         \
      for (int j_ = 0; j_ < 2; ++j_) {                                          \
        acc[(ib) + i_][(jb) + j_] = __builtin_amdgcn_mfma_f32_16x16x32_bf16(    \
            af[i_][0], bfr[(jb) + j_][0], acc[(ib) + i_][(jb) + j_], 0, 0, 0);  \
        acc[(ib) + i_][(jb) + j_] = __builtin_amdgcn_mfma_f32_16x16x32_bf16(    \
            af[i_][1], bfr[(jb) + j_][1], acc[(ib) + i_][(jb) + j_], 0, 0, 0);  \
      }                                                                         \
    }                                                                           \
    __builtin_amdgcn_s_setprio(0);                                              \
  } while (0)

  // prologue: tile0 fully + tile1 hA0,hB0,hB1 in flight; drain tile0.
  STAGE_A(0, 0, 0);  // hA0(0)
  STAGE_B(0, 0, 0);  // hB0(0)
  STAGE_B(0, 0, 1);  // hB1(0)
  STAGE_A(0, 0, 1);  // hA1(0)
  STAGE_A(1, 1, 0);  // hA0(1)
  STAGE_B(1, 1, 0);  // hB0(1)
  STAGE_B(1, 1, 1);  // hB1(1)
  asm volatile("s_waitcnt vmcnt(6)" ::: "memory");
  __builtin_amdgcn_s_barrier();
  asm volatile("" ::: "memory");

  bf16x8 af[4][2], bfr[4][2];
  for (int it = 0; it < 8; ++it) {
    const bool nl = it < 7;
    const int T2 = 2 * it + 2, T3 = 2 * it + 3;

    // ph1: q00(T0) — read A-lo(b0)+B-lo(b0); stage hA1(T1)
    RD_A(0, wm); RD_B(0, 0);
    STAGE_A(1, 2 * it + 1, 1);
    PBAR();
    MFQ(0, 0);
    PBAR();

    // ph2: q01(T0) — read B-hi(b0); stage hA0(T2)
    RD_B(0, 2);
    if (nl) STAGE_A(0, T2, 0);
    PBAR();
    MFQ(0, 2);
    PBAR();

    // ph3: q10(T0) — read A-hi(b0); stage hB0(T2)
    RD_A(0, wm + 64);
    if (nl) STAGE_B(0, T2, 0);
    PBAR();
    MFQ(4, 0);
    PBAR();

    // ph4: q11(T0) — no reads; stage hB1(T2); vmcnt
    if (nl) STAGE_B(0, T2, 1);
    PBAR();
    MFQ(4, 2);
    if (nl) asm volatile("s_waitcnt vmcnt(6)" ::: "memory");
    else    asm volatile("s_waitcnt vmcnt(0)" ::: "memory");
    PBAR();

    // ph5: q00(T1) — read A-lo(b1)+B-lo(b1); stage hA1(T2)
    RD_A(1, wm); RD_B(1, 0);
    if (nl) STAGE_A(0, T2, 1);
    PBAR();
    MFQ(0, 0);
    PBAR();

    // ph6: q01(T1) — read B-hi(b1); stage hA0(T3)
    RD_B(1, 2);
    if (nl) STAGE_A(1, T3, 0);
    PBAR();
    MFQ(0, 2);
    PBAR();

    // ph7: q10(T1) — read A-hi(b1); stage hB0(T3)
    RD_A(1, wm + 64);
    if (nl) STAGE_B(1, T3, 0);
    PBAR();
    MFQ(4, 0);
    PBAR();

    // ph8: q11(T1) — stage hB1(T3); vmcnt(6)
    if (nl) STAGE_B(1, T3, 1);
    PBAR();
    MFQ(4, 2);
    if (nl) asm volatile("s_waitcnt vmcnt(6)" ::: "memory");
    PBAR();
  }
#undef STAGE_A
#undef STAGE_B
#undef PBAR
#undef RD_A
#undef RD_B
#undef MFQ

  const int which = nBase >> 10;
  const float* bias = which == 0 ? b0 : (which == 1 ? b1 : b2);
  unsigned short* dst = which == 0 ? oQ : (which == 1 ? oK : oVt);
  const float scl = which == 0 ? 0.1803368801f : 1.0f;  // 0.125*log2(e) on Q
#pragma unroll
  for (int i = 0; i < 8; i++)
#pragma unroll
    for (int r = 0; r < 4; r++) {
      const int m = mBase + wm + i * 16 + quad * 4 + r;
      const int b = m >> 11, tp = m & 2047;
#pragma unroll
      for (int j = 0; j < 4; j++) {
        const int n = nBase + wn + j * 16 + l16;
        const int nl2 = n & 1023, h = nl2 >> 6, d = nl2 & 63;
        const unsigned short v = f2bf((acc[i][j][r] + bias[nl2]) * scl);
        if (which < 2) dst[((size_t)(b * HH + h) * TT + tp) * HDD + d] = v;
        else           dst[((size_t)(b * HH + h) * HDD + d) * TT + tp] = v;
      }
    }
}

// Output projection: 128x128 tile, BK=32 dbuf, counted vmcnt, 512 threads,
// grid (32,8) = 256 blocks (unchanged from R13).
__global__ __launch_bounds__(512) void gemm_proj(
    const unsigned short* __restrict__ A, const unsigned short* __restrict__ W,
    const float* __restrict__ bias, float* __restrict__ out)
{
  __shared__ unsigned short As[2][128][32];
  __shared__ unsigned short Bs[2][128][32];
  const int t = threadIdx.x;
  const int wv = __builtin_amdgcn_readfirstlane(t >> 6);  // 0..7
  const int ln = t & 63;
  const int l16 = ln & 15;
  const int quad = ln >> 4;
  const int mBase = blockIdx.x * 128;
  const int nBase = blockIdx.y * 128;
  const int wm = (wv >> 2) * 64;        // {0,64}
  const int wn = (wv & 3) * 32;         // {0,32,64,96}

  f32x4 acc[4][2];
#pragma unroll
  for (int i = 0; i < 4; i++)
#pragma unroll
    for (int j = 0; j < 2; j++) acc[i][j] = (f32x4){0.f, 0.f, 0.f, 0.f};

  const int rloc = t >> 2;                               // 0..127
  const int csrc = ((t & 3) ^ ((t >> 3) & 3)) * 8;
  const unsigned short* gA = A + (size_t)(mBase + rloc) * CC + csrc;
  const unsigned short* gB = W + (size_t)(nBase + rloc) * CC + csrc;
  const int sw = (quad ^ ((l16 >> 1) & 3)) * 8;

#define STAGE(b, kt)                                                       \
  do {                                                                     \
    const size_t ko = (size_t)(kt) * 32;                                   \
    gload_lds16(gA + ko, &As[b][0][0] + t * 8);                            \
    gload_lds16(gB + ko, &Bs[b][0][0] + t * 8);                            \
  } while (0)

  STAGE(0, 0);
  for (int kt = 0; kt < 32; ++kt) {
    const int cur = kt & 1;
    if (kt < 31) {
      STAGE(cur ^ 1, kt + 1);
      asm volatile("s_waitcnt vmcnt(2)" ::: "memory");
    } else {
      asm volatile("s_waitcnt vmcnt(0)" ::: "memory");
    }
    __builtin_amdgcn_s_barrier();
    asm volatile("" ::: "memory");
    bf16x8 af[4], bfr[2];
#pragma unroll
    for (int i = 0; i < 4; ++i) af[i] = *(const bf16x8*)&As[cur][wm + i * 16 + l16][sw];
#pragma unroll
    for (int j = 0; j < 2; ++j) bfr[j] = *(const bf16x8*)&Bs[cur][wn + j * 16 + l16][sw];
    __builtin_amdgcn_s_setprio(1);
#pragma unroll
    for (int i = 0; i < 4; ++i)
#pragma unroll
      for (int j = 0; j < 2; ++j)
        acc[i][j] = __builtin_amdgcn_mfma_f32_16x16x32_bf16(af[i], bfr[j], acc[i][j], 0, 0, 0);
    __builtin_amdgcn_s_setprio(0);
    asm volatile("" ::: "memory");
    __builtin_amdgcn_s_barrier();
    asm volatile("" ::: "memory");
  }
#undef STAGE

#pragma unroll
  for (int i = 0; i < 4; i++)
#pragma unroll
    for (int r = 0; r < 4; r++) {
      const int m = mBase + wm + i * 16 + quad * 4 + r;
#pragma unroll
      for (int j = 0; j < 2; j++) {
        const int n = nBase + wn + j * 16 + l16;
        out[(size_t)m * CC + n] = acc[i][j][r] + bias[n];
      }
    }
}

// MFMA bf16 flash attention — R7 paired structure (unchanged this round).
__global__ __launch_bounds__(256, 2) void attn_mfma(
    const unsigned short* __restrict__ Q, const unsigned short* __restrict__ K,
    const unsigned short* __restrict__ Vt, unsigned short* __restrict__ y)
{
  __shared__ unsigned short QP[128][72];      // Q tiles; becomes P after qfrag extract
  __shared__ unsigned short Ks[2][64][72];
  __shared__ unsigned short Vts[2][64][72];

  const int t = threadIdx.x;
  const int a = blockIdx.x;        // 0..15
  const int bh = blockIdx.y;       // 0..31
  const int wave = t >> 6;
  const int lane = t & 63;
  const int l16 = lane & 15;
  const int quad = lane >> 4;

  const size_t base = (size_t)bh * TT * HDD;
  const int qtL = a, qtH = 31 - a;
  const int qBaseL = qtL * 64, qBaseH = qtH * 64;

  // stage Q: rows 0..63 = lo tile, 64..127 = hi tile
#pragma unroll
  for (int p = 0; p < 4; p++) {
    const int c = p * 256 + t;
    const int r = c >> 3, off = (c & 7) * 8;
    const int srcRow = (r < 64) ? (qBaseL + r) : (qBaseH + r - 64);
    *(uint4*)&QP[r][off] = *(const uint4*)(Q + base + (size_t)srcRow * HDD + off);
  }

  // K/V register prefetch (tile 0)
  const int sr = t >> 2, sc = (t & 3) * 8;
  const unsigned short* kbase = K + base + (size_t)sr * HDD + sc;
  const unsigned short* vbase = Vt + base + (size_t)sr * TT + sc;
  uint4 kr0 = *(const uint4*)(kbase);
  uint4 kr1 = *(const uint4*)(kbase + 32);
  uint4 vr0 = *(const uint4*)(vbase);
  uint4 vr1 = *(const uint4*)(vbase + 32);
  __syncthreads();  // Q staged

  bf16x8 qfL0 = *(const bf16x8*)&QP[wave * 16 + l16][quad * 8];
  bf16x8 qfL1 = *(const bf16x8*)&QP[wave * 16 + l16][32 + quad * 8];
  bf16x8 qfH0 = *(const bf16x8*)&QP[64 + wave * 16 + l16][quad * 8];
  bf16x8 qfH1 = *(const bf16x8*)&QP[64 + wave * 16 + l16][32 + quad * 8];
  unsigned short (*PtH)[72] = (unsigned short (*)[72])&QP[wave * 16];
  unsigned short (*PtL)[72] = (unsigned short (*)[72])&QP[64 + wave * 16];

  float lL = 0.f, lH = 0.f;  // per-lane partial; cross-quad reduce deferred
  f32x4 OfrL[4], OfrH[4];
#pragma unroll
  for (int dt = 0; dt < 4; dt++) {
    OfrL[dt] = (f32x4){0.f, 0.f, 0.f, 0.f};
    OfrH[dt] = (f32x4){0.f, 0.f, 0.f, 0.f};
  }

  for (int kt = 0; kt <= qtH; kt++) {
    const int buf = kt & 1;
    *(uint4*)&Ks[buf][sr][sc]       = kr0;
    *(uint4*)&Ks[buf][sr][sc + 32]  = kr1;
    *(uint4*)&Vts[buf][sr][sc]      = vr0;
    *(uint4*)&Vts[buf][sr][sc + 32] = vr1;
    __syncthreads();  // ONLY barrier: commits visible; prior-buf readers done
    if (kt < qtH) {
      kr0 = *(const uint4*)(kbase + (size_t)(kt + 1) * 64 * HDD);
      kr1 = *(const uint4*)(kbase + (size_t)(kt + 1) * 64 * HDD + 32);
      vr0 = *(const uint4*)(vbase + (kt + 1) * 64);
      vr1 = *(const uint4*)(vbase + (kt + 1) * 64 + 32);
    }
    const bool doLo = (kt <= qtL);

    // S^T = K Q^T
    f32x4 StH[4], StL[4];
#pragma unroll
    for (int ct = 0; ct < 4; ct++) {
      bf16x8 a0 = *(const bf16x8*)&Ks[buf][ct * 16 + l16][quad * 8];
      bf16x8 a1 = *(const bf16x8*)&Ks[buf][ct * 16 + l16][32 + quad * 8];
      f32x4 s = (f32x4){0.f, 0.f, 0.f, 0.f};
      s = __builtin_amdgcn_mfma_f32_16x16x32_bf16(a0, qfH0, s, 0, 0, 0);
      s = __builtin_amdgcn_mfma_f32_16x16x32_bf16(a1, qfH1, s, 0, 0, 0);
      StH[ct] = s;
      if (doLo) {
        f32x4 s2 = (f32x4){0.f, 0.f, 0.f, 0.f};
        s2 = __builtin_amdgcn_mfma_f32_16x16x32_bf16(a0, qfL0, s2, 0, 0, 0);
        s2 = __builtin_amdgcn_mfma_f32_16x16x32_bf16(a1, qfL1, s2, 0, 0, 0);
        StL[ct] = s2;
      }
    }

    // softmax hi (mask only on the diagonal iteration — wave-uniform branch)
    if (kt == qtH) {
#pragma unroll
      for (int ct = 0; ct < 4; ct++) {
        float p[4];
#pragma unroll
        for (int r = 0; r < 4; r++) {
          float pv = fexp2(StH[ct][r]);
          if (ct * 16 + quad * 4 + r > wave * 16 + l16) pv = 0.f;
          p[r] = pv;
        }
        lH += (p[0] + p[1]) + (p[2] + p[3]);
        uint2 pk = {pk_trunc(p[0], p[1]), pk_trunc(p[2], p[3])};
        *(uint2*)&PtH[l16][ct * 16 + quad * 4] = pk;
      }
    } else {
#pragma unroll
      for (int ct = 0; ct < 4; ct++) {
        float p[4];
#pragma unroll
        for (int r = 0; r < 4; r++) p[r] = fexp2(StH[ct][r]);
        lH += (p[0] + p[1]) + (p[2] + p[3]);
        uint2 pk = {pk_trunc(p[0], p[1]), pk_trunc(p[2], p[3])};
        *(uint2*)&PtH[l16][ct * 16 + quad * 4] = pk;
      }
    }
    if (doLo) {
      if (kt == qtL) {
#pragma unroll
        for (int ct = 0; ct < 4; ct++) {
          float p[4];
#pragma unroll
          for (int r = 0; r < 4; r++) {
            float pv = fexp2(StL[ct][r]);
            if (ct * 16 + quad * 4 + r > wave * 16 + l16) pv = 0.f;
            p[r] = pv;
          }
          lL += (p[0] + p[1]) + (p[2] + p[3]);
          uint2 pk = {pk_trunc(p[0], p[1]), pk_trunc(p[2], p[3])};
          *(uint2*)&PtL[l16][ct * 16 + quad * 4] = pk;
        }
      } else {
#pragma unroll
        for (int ct = 0; ct < 4; ct++) {
          float p[4];
#pragma unroll
          for (int r = 0; r < 4; r++) p[r] = fexp2(StL[ct][r]);
          lL += (p[0] + p[1]) + (p[2] + p[3]);
          uint2 pk = {pk_trunc(p[0], p[1]), pk_trunc(p[2], p[3])};
          *(uint2*)&PtL[l16][ct * 16 + quad * 4] = pk;
        }
      }
    }

    // O += P V (Pt wave-private: in-wave lgkmcnt ordering, no barrier)
    bf16x8 paH0 = *(const bf16x8*)&PtH[l16][quad * 8];
    bf16x8 paH1 = *(const bf16x8*)&PtH[l16][32 + quad * 8];
    bf16x8 paL0, paL1;
    if (doLo) {
      paL0 = *(const bf16x8*)&PtL[l16][quad * 8];
      paL1 = *(const bf16x8*)&PtL[l16][32 + quad * 8];
    }
#pragma unroll
    for (int dt = 0; dt < 4; dt++) {
      bf16x8 vb0 = *(const bf16x8*)&Vts[buf][dt * 16 + l16][quad * 8];
      bf16x8 vb1 = *(const bf16x8*)&Vts[buf][dt * 16 + l16][32 + quad * 8];
      OfrH[dt] = __builtin_amdgcn_mfma_f32_16x16x32_bf16(paH0, vb0, OfrH[dt], 0, 0, 0);
      OfrH[dt] = __builtin_amdgcn_mfma_f32_16x16x32_bf16(paH1, vb1, OfrH[dt], 0, 0, 0);
      if (doLo) {
        OfrL[dt] = __builtin_amdgcn_mfma_f32_16x16x32_bf16(paL0, vb0, OfrL[dt], 0, 0, 0);
        OfrL[dt] = __builtin_amdgcn_mfma_f32_16x16x32_bf16(paL1, vb1, OfrL[dt], 0, 0, 0);
      }
    }
    // no trailing barrier: next iter commits the OTHER buffer
  }

  // deferred cross-quad l reduction
  lL += __shfl_xor(lL, 16, 64); lL += __shfl_xor(lL, 32, 64);
  lH += __shfl_xor(lH, 16, 64); lH += __shfl_xor(lH, 32, 64);

  const int b = bh >> 4, h = bh & 15;
  float lRowL[4], lRowH[4];
#pragma unroll
  for (int r = 0; r < 4; r++) {
    lRowL[r] = __shfl(lL, quad * 4 + r, 16);
    lRowH[r] = __shfl(lH, quad * 4 + r, 16);
  }
#pragma unroll
  for (int r = 0; r < 4; r++) {
    const int qL = qBaseL + wave * 16 + quad * 4 + r;
    const int qH = qBaseH + wave * 16 + quad * 4 + r;
    const float invL = 1.0f / lRowL[r];
    const float invH = 1.0f / lRowH[r];
    unsigned short* ypL = y + ((size_t)(b * TT + qL)) * CC + h * 64 + l16;
    unsigned short* ypH = y + ((size_t)(b * TT + qH)) * CC + h * 64 + l16;
#pragma unroll
    for (int dt = 0; dt < 4; dt++) {
      ypL[dt * 16] = f2bf(OfrL[dt][r] * invL);
      ypH[dt * 16] = f2bf(OfrH[dt][r] * invH);
    }
  }
}

extern "C" void kernel_launch(void* const* d_in, const int* in_sizes, int n_in,
                              void* d_out, int out_size, void* d_ws, size_t ws_size,
                              hipStream_t stream) {
  const float* x  = (const float*)d_in[0];
  const float* Wq = (const float*)d_in[1];
  const float* bq = (const float*)d_in[2];
  const float* Wk = (const float*)d_in[3];
  const float* bk = (const float*)d_in[4];
  const float* Wv = (const float*)d_in[5];
  const float* bv = (const float*)d_in[6];
  const float* Wp = (const float*)d_in[7];
  const float* bp = (const float*)d_in[8];

  const size_t M4 = 4194304, M1 = 1048576;
  unsigned short* xb   = (unsigned short*)d_ws;  // 4M
  unsigned short* wqb  = xb + M4;                // wq,wk,wv,wp contiguous
  unsigned short* wpb  = wqb + 3 * M1;
  unsigned short* wsQ  = wpb + M1;               // [B,H,T,HD] (pre-scaled)
  unsigned short* wsK  = wsQ + M4;               // [B,H,T,HD]
  unsigned short* wsVt = wsK + M4;               // [B,H,HD,T]
  unsigned short* yb   = wsVt + M4;              // [B,T,C] bf16

  convert_all<<<4096, 256, 0, stream>>>(x, Wq, Wk, Wv, Wp, xb);
  gemm_mfma<<<dim3(16, 12), 512, 0, stream>>>(xb, wqb, bq, bk, bv,
                                              wsQ, wsK, wsVt);
  attn_mfma<<<dim3(16, BB * HH), 256, 0, stream>>>(wsQ, wsK, wsVt, yb);
  gemm_proj<<<dim3(32, 8), 512, 0, stream>>>(yb, wpb, bp, (float*)d_out);
}

// Round 6
// 186.302 us; speedup vs baseline: 1.1079x; 1.0926x over previous
//
#include <hip/hip_runtime.h>
#include <hip/hip_bf16.h>

#define BB 2
#define TT 2048
#define CC 1024
#define HH 16
#define HDD 64

typedef __attribute__((ext_vector_type(8))) short bf16x8;
typedef __attribute__((ext_vector_type(4))) float f32x4;

static __device__ __forceinline__ unsigned short f2bf(float f) {
  union { float f; unsigned u; } v; v.f = f;
  unsigned r = v.u + 0x7fffu + ((v.u >> 16) & 1u);  // RNE
  return (unsigned short)(r >> 16);
}

static __device__ __forceinline__ unsigned fbits(float f) {
  union { float f; unsigned u; } v; v.f = f; return v.u;
}

// pack two fp32 -> two bf16 (truncate) in ONE v_perm_b32
static __device__ __forceinline__ unsigned pk_trunc(float lo, float hi) {
  return __builtin_amdgcn_perm(fbits(hi), fbits(lo), 0x07060302u);
}

// raw v_exp_f32 (args bounded; skips OCML range/subnormal fixup)
static __device__ __forceinline__ float fexp2(float x) {
#if __has_builtin(__builtin_amdgcn_exp2f)
  return __builtin_amdgcn_exp2f(x);
#else
  return exp2f(x);
#endif
}

static __device__ __forceinline__ void gload_lds16(const unsigned short* g, unsigned short* l) {
  __builtin_amdgcn_global_load_lds((const __attribute__((address_space(1))) void*)g,
                                   (__attribute__((address_space(3))) void*)l, 16, 0, 0);
}

// fp32 -> bf16 for x (4M), Wq,Wk,Wv,Wp (1M each), into contiguous dst.
__global__ __launch_bounds__(256) void convert_all(
    const float* __restrict__ x, const float* __restrict__ Wq,
    const float* __restrict__ Wk, const float* __restrict__ Wv,
    const float* __restrict__ Wp, unsigned short* __restrict__ dst)
{
  const size_t M4 = 4194304, M1 = 1048576;
  const size_t e = ((size_t)blockIdx.x * 256 + threadIdx.x) * 8;
  const float* src; size_t off;
  if (e < M4)            { src = x;  off = e; }
  else if (e < M4 + M1)  { src = Wq; off = e - M4; }
  else if (e < M4 + 2*M1){ src = Wk; off = e - M4 - M1; }
  else if (e < M4 + 3*M1){ src = Wv; off = e - M4 - 2*M1; }
  else                   { src = Wp; off = e - M4 - 3*M1; }
  float4 a = *(const float4*)(src + off);
  float4 c = *(const float4*)(src + off + 4);
  unsigned short buf[8] = {f2bf(a.x), f2bf(a.y), f2bf(a.z), f2bf(a.w),
                           f2bf(c.x), f2bf(c.y), f2bf(c.z), f2bf(c.w)};
  *(uint4*)(dst + e) = *(const uint4*)buf;
}

// ---------------------------------------------------------------------------
// R17: R13 2-phase 128x128 GEMM (best measured: 42.8us, 3 blocks/CU) +
// TRIPLE-buffered LDS with 2-iteration prefetch distance.
// R14/R15/R16 (256^2 8-phase, 1 block/CU) all ~61us regardless of schedule:
// at 1 block/CU the phase pipeline (~600cy deep) < HBM latency (~900cy) and
// there is no cross-block TLP to fill it. Reverted per pre-commitment.
// Tri-buffer mechanics (per iter kt):
//   STAGE tile kt+2 -> buf (kt+2)%3   [= tile kt-1's buffer; its readers
//                                       finished before prev trailing BAR]
//   s_waitcnt vmcnt(8): drains tile kt (issued 2 iters ~2600cy ago -> free),
//                       keeps kt+1/kt+2 in flight (never drains young loads)
//   BAR; ds_read buf kt%3; 16 MFMA; BAR
// Tail: kt==30 vmcnt(4), kt==31 vmcnt(0). LDS 48KB -> still 3 blocks/CU.
// Swizzle unchanged (proven: conflicts 0).
// ---------------------------------------------------------------------------

// bf16 MFMA GEMM for fused QKV. grid (32,24), 256 threads.
__global__ __launch_bounds__(256) void gemm_mfma(
    const unsigned short* __restrict__ A, const unsigned short* __restrict__ W,
    const float* __restrict__ b0, const float* __restrict__ b1, const float* __restrict__ b2,
    unsigned short* __restrict__ oQ, unsigned short* __restrict__ oK,
    unsigned short* __restrict__ oVt)
{
  __shared__ unsigned short As[3][128][32];
  __shared__ unsigned short Bs[3][128][32];
  const int t = threadIdx.x;
  const int wv = __builtin_amdgcn_readfirstlane(t >> 6);
  const int ln = t & 63;
  const int l16 = ln & 15;
  const int quad = ln >> 4;
  const int mBase = blockIdx.x * 128;
  const int nBase = blockIdx.y * 128;
  const int wm = (wv >> 1) * 64, wn = (wv & 1) * 64;

  f32x4 acc[4][4];
#pragma unroll
  for (int i = 0; i < 4; i++)
#pragma unroll
    for (int j = 0; j < 4; j++) acc[i][j] = (f32x4){0.f, 0.f, 0.f, 0.f};

  // staging: thread t -> row t>>2 (and +64 on the 2nd issue), phys chunk t&3.
  // source column pre-swizzled: logical chunk = (t&3) ^ ((row>>1)&3).
  const int rloc = t >> 2;
  const int csrc = ((t & 3) ^ ((t >> 3) & 3)) * 8;
  const unsigned short* gA = A + (size_t)(mBase + rloc) * CC + csrc;
  const unsigned short* gB = W + (size_t)(nBase + rloc) * CC + csrc;
  // ds_read swizzle: row = wm|wn + i*16 + l16 -> (row>>1)&3 == (l16>>1)&3
  const int sw = (quad ^ ((l16 >> 1) & 3)) * 8;

#define STAGE(b, kt)                                                       \
  do {                                                                     \
    const size_t ko = (size_t)(kt) * 32;                                   \
    gload_lds16(gA + ko,           &As[b][0][0] + t * 8);                  \
    gload_lds16(gA + ko + 64 * CC, &As[b][64][0] + t * 8);                 \
    gload_lds16(gB + ko,           &Bs[b][0][0] + t * 8);                  \
    gload_lds16(gB + ko + 64 * CC, &Bs[b][64][0] + t * 8);                 \
  } while (0)

  STAGE(0, 0);
  STAGE(1, 1);
  int cur = 0, nxt2 = 2;   // buffer of tile kt, buffer of tile kt+2
  for (int kt = 0; kt < 32; ++kt) {
    if (kt < 30) {
      STAGE(nxt2, kt + 2);
      asm volatile("s_waitcnt vmcnt(8)" ::: "memory");
    } else if (kt == 30) {
      asm volatile("s_waitcnt vmcnt(4)" ::: "memory");
    } else {
      asm volatile("s_waitcnt vmcnt(0)" ::: "memory");
    }
    __builtin_amdgcn_s_barrier();
    asm volatile("" ::: "memory");
    bf16x8 af[4], bfr[4];
#pragma unroll
    for (int i = 0; i < 4; ++i) af[i] = *(const bf16x8*)&As[cur][wm + i * 16 + l16][sw];
#pragma unroll
    for (int j = 0; j < 4; ++j) bfr[j] = *(const bf16x8*)&Bs[cur][wn + j * 16 + l16][sw];
    __builtin_amdgcn_s_setprio(1);
#pragma unroll
    for (int i = 0; i < 4; ++i)
#pragma unroll
      for (int j = 0; j < 4; ++j)
        acc[i][j] = __builtin_amdgcn_mfma_f32_16x16x32_bf16(af[i], bfr[j], acc[i][j], 0, 0, 0);
    __builtin_amdgcn_s_setprio(0);
    asm volatile("" ::: "memory");
    __builtin_amdgcn_s_barrier();
    asm volatile("" ::: "memory");
    cur = (cur == 2) ? 0 : cur + 1;
    nxt2 = (nxt2 == 2) ? 0 : nxt2 + 1;
  }
#undef STAGE

  const int which = nBase >> 10;
  const float* bias = which == 0 ? b0 : (which == 1 ? b1 : b2);
  unsigned short* dst = which == 0 ? oQ : (which == 1 ? oK : oVt);
  const float scl = which == 0 ? 0.1803368801f : 1.0f;  // 0.125*log2(e) on Q
#pragma unroll
  for (int i = 0; i < 4; i++)
#pragma unroll
    for (int r = 0; r < 4; r++) {
      const int m = mBase + wm + i * 16 + quad * 4 + r;
      const int b = m >> 11, tp = m & 2047;
#pragma unroll
      for (int j = 0; j < 4; j++) {
        const int n = nBase + wn + j * 16 + l16;
        const int nl = n & 1023, h = nl >> 6, d = nl & 63;
        const unsigned short v = f2bf((acc[i][j][r] + bias[nl]) * scl);
        if (which < 2) dst[((size_t)(b * HH + h) * TT + tp) * HDD + d] = v;
        else           dst[((size_t)(b * HH + h) * HDD + d) * TT + tp] = v;
      }
    }
}

// Output projection: 128x128 tile, BK=32 tri-buffer, 512 threads, grid (32,8).
__global__ __launch_bounds__(512) void gemm_proj(
    const unsigned short* __restrict__ A, const unsigned short* __restrict__ W,
    const float* __restrict__ bias, float* __restrict__ out)
{
  __shared__ unsigned short As[3][128][32];
  __shared__ unsigned short Bs[3][128][32];
  const int t = threadIdx.x;
  const int wv = __builtin_amdgcn_readfirstlane(t >> 6);  // 0..7
  const int ln = t & 63;
  const int l16 = ln & 15;
  const int quad = ln >> 4;
  const int mBase = blockIdx.x * 128;
  const int nBase = blockIdx.y * 128;
  const int wm = (wv >> 2) * 64;        // {0,64}
  const int wn = (wv & 3) * 32;         // {0,32,64,96}

  f32x4 acc[4][2];
#pragma unroll
  for (int i = 0; i < 4; i++)
#pragma unroll
    for (int j = 0; j < 2; j++) acc[i][j] = (f32x4){0.f, 0.f, 0.f, 0.f};

  const int rloc = t >> 2;                               // 0..127
  const int csrc = ((t & 3) ^ ((t >> 3) & 3)) * 8;
  const unsigned short* gA = A + (size_t)(mBase + rloc) * CC + csrc;
  const unsigned short* gB = W + (size_t)(nBase + rloc) * CC + csrc;
  const int sw = (quad ^ ((l16 >> 1) & 3)) * 8;

#define STAGE(b, kt)                                                       \
  do {                                                                     \
    const size_t ko = (size_t)(kt) * 32;                                   \
    gload_lds16(gA + ko, &As[b][0][0] + t * 8);                            \
    gload_lds16(gB + ko, &Bs[b][0][0] + t * 8);                            \
  } while (0)

  STAGE(0, 0);
  STAGE(1, 1);
  int cur = 0, nxt2 = 2;
  for (int kt = 0; kt < 32; ++kt) {
    if (kt < 30) {
      STAGE(nxt2, kt + 2);
      asm volatile("s_waitcnt vmcnt(4)" ::: "memory");
    } else if (kt == 30) {
      asm volatile("s_waitcnt vmcnt(2)" ::: "memory");
    } else {
      asm volatile("s_waitcnt vmcnt(0)" ::: "memory");
    }
    __builtin_amdgcn_s_barrier();
    asm volatile("" ::: "memory");
    bf16x8 af[4], bfr[2];
#pragma unroll
    for (int i = 0; i < 4; ++i) af[i] = *(const bf16x8*)&As[cur][wm + i * 16 + l16][sw];
#pragma unroll
    for (int j = 0; j < 2; ++j) bfr[j] = *(const bf16x8*)&Bs[cur][wn + j * 16 + l16][sw];
    __builtin_amdgcn_s_setprio(1);
#pragma unroll
    for (int i = 0; i < 4; ++i)
#pragma unroll
      for (int j = 0; j < 2; ++j)
        acc[i][j] = __builtin_amdgcn_mfma_f32_16x16x32_bf16(af[i], bfr[j], acc[i][j], 0, 0, 0);
    __builtin_amdgcn_s_setprio(0);
    asm volatile("" ::: "memory");
    __builtin_amdgcn_s_barrier();
    asm volatile("" ::: "memory");
    cur = (cur == 2) ? 0 : cur + 1;
    nxt2 = (nxt2 == 2) ? 0 : nxt2 + 1;
  }
#undef STAGE

#pragma unroll
  for (int i = 0; i < 4; i++)
#pragma unroll
    for (int r = 0; r < 4; r++) {
      const int m = mBase + wm + i * 16 + quad * 4 + r;
#pragma unroll
      for (int j = 0; j < 2; j++) {
        const int n = nBase + wn + j * 16 + l16;
        out[(size_t)m * CC + n] = acc[i][j][r] + bias[n];
      }
    }
}

// MFMA bf16 flash attention — R7 paired structure (unchanged this round).
__global__ __launch_bounds__(256, 2) void attn_mfma(
    const unsigned short* __restrict__ Q, const unsigned short* __restrict__ K,
    const unsigned short* __restrict__ Vt, unsigned short* __restrict__ y)
{
  __shared__ unsigned short QP[128][72];      // Q tiles; becomes P after qfrag extract
  __shared__ unsigned short Ks[2][64][72];
  __shared__ unsigned short Vts[2][64][72];

  const int t = threadIdx.x;
  const int a = blockIdx.x;        // 0..15
  const int bh = blockIdx.y;       // 0..31
  const int wave = t >> 6;
  const int lane = t & 63;
  const int l16 = lane & 15;
  const int quad = lane >> 4;

  const size_t base = (size_t)bh * TT * HDD;
  const int qtL = a, qtH = 31 - a;
  const int qBaseL = qtL * 64, qBaseH = qtH * 64;

  // stage Q: rows 0..63 = lo tile, 64..127 = hi tile
#pragma unroll
  for (int p = 0; p < 4; p++) {
    const int c = p * 256 + t;
    const int r = c >> 3, off = (c & 7) * 8;
    const int srcRow = (r < 64) ? (qBaseL + r) : (qBaseH + r - 64);
    *(uint4*)&QP[r][off] = *(const uint4*)(Q + base + (size_t)srcRow * HDD + off);
  }

  // K/V register prefetch (tile 0)
  const int sr = t >> 2, sc = (t & 3) * 8;
  const unsigned short* kbase = K + base + (size_t)sr * HDD + sc;
  const unsigned short* vbase = Vt + base + (size_t)sr * TT + sc;
  uint4 kr0 = *(const uint4*)(kbase);
  uint4 kr1 = *(const uint4*)(kbase + 32);
  uint4 vr0 = *(const uint4*)(vbase);
  uint4 vr1 = *(const uint4*)(vbase + 32);
  __syncthreads();  // Q staged

  bf16x8 qfL0 = *(const bf16x8*)&QP[wave * 16 + l16][quad * 8];
  bf16x8 qfL1 = *(const bf16x8*)&QP[wave * 16 + l16][32 + quad * 8];
  bf16x8 qfH0 = *(const bf16x8*)&QP[64 + wave * 16 + l16][quad * 8];
  bf16x8 qfH1 = *(const bf16x8*)&QP[64 + wave * 16 + l16][32 + quad * 8];
  unsigned short (*PtH)[72] = (unsigned short (*)[72])&QP[wave * 16];
  unsigned short (*PtL)[72] = (unsigned short (*)[72])&QP[64 + wave * 16];

  float lL = 0.f, lH = 0.f;  // per-lane partial; cross-quad reduce deferred
  f32x4 OfrL[4], OfrH[4];
#pragma unroll
  for (int dt = 0; dt < 4; dt++) {
    OfrL[dt] = (f32x4){0.f, 0.f, 0.f, 0.f};
    OfrH[dt] = (f32x4){0.f, 0.f, 0.f, 0.f};
  }

  for (int kt = 0; kt <= qtH; kt++) {
    const int buf = kt & 1;
    *(uint4*)&Ks[buf][sr][sc]       = kr0;
    *(uint4*)&Ks[buf][sr][sc + 32]  = kr1;
    *(uint4*)&Vts[buf][sr][sc]      = vr0;
    *(uint4*)&Vts[buf][sr][sc + 32] = vr1;
    __syncthreads();  // ONLY barrier: commits visible; prior-buf readers done
    if (kt < qtH) {
      kr0 = *(const uint4*)(kbase + (size_t)(kt + 1) * 64 * HDD);
      kr1 = *(const uint4*)(kbase + (size_t)(kt + 1) * 64 * HDD + 32);
      vr0 = *(const uint4*)(vbase + (kt + 1) * 64);
      vr1 = *(const uint4*)(vbase + (kt + 1) * 64 + 32);
    }
    const bool doLo = (kt <= qtL);

    // S^T = K Q^T
    f32x4 StH[4], StL[4];
#pragma unroll
    for (int ct = 0; ct < 4; ct++) {
      bf16x8 a0 = *(const bf16x8*)&Ks[buf][ct * 16 + l16][quad * 8];
      bf16x8 a1 = *(const bf16x8*)&Ks[buf][ct * 16 + l16][32 + quad * 8];
      f32x4 s = (f32x4){0.f, 0.f, 0.f, 0.f};
      s = __builtin_amdgcn_mfma_f32_16x16x32_bf16(a0, qfH0, s, 0, 0, 0);
      s = __builtin_amdgcn_mfma_f32_16x16x32_bf16(a1, qfH1, s, 0, 0, 0);
      StH[ct] = s;
      if (doLo) {
        f32x4 s2 = (f32x4){0.f, 0.f, 0.f, 0.f};
        s2 = __builtin_amdgcn_mfma_f32_16x16x32_bf16(a0, qfL0, s2, 0, 0, 0);
        s2 = __builtin_amdgcn_mfma_f32_16x16x32_bf16(a1, qfL1, s2, 0, 0, 0);
        StL[ct] = s2;
      }
    }

    // softmax hi (mask only on the diagonal iteration — wave-uniform branch)
    if (kt == qtH) {
#pragma unroll
      for (int ct = 0; ct < 4; ct++) {
        float p[4];
#pragma unroll
        for (int r = 0; r < 4; r++) {
          float pv = fexp2(StH[ct][r]);
          if (ct * 16 + quad * 4 + r > wave * 16 + l16) pv = 0.f;
          p[r] = pv;
        }
        lH += (p[0] + p[1]) + (p[2] + p[3]);
        uint2 pk = {pk_trunc(p[0], p[1]), pk_trunc(p[2], p[3])};
        *(uint2*)&PtH[l16][ct * 16 + quad * 4] = pk;
      }
    } else {
#pragma unroll
      for (int ct = 0; ct < 4; ct++) {
        float p[4];
#pragma unroll
        for (int r = 0; r < 4; r++) p[r] = fexp2(StH[ct][r]);
        lH += (p[0] + p[1]) + (p[2] + p[3]);
        uint2 pk = {pk_trunc(p[0], p[1]), pk_trunc(p[2], p[3])};
        *(uint2*)&PtH[l16][ct * 16 + quad * 4] = pk;
      }
    }
    if (doLo) {
      if (kt == qtL) {
#pragma unroll
        for (int ct = 0; ct < 4; ct++) {
          float p[4];
#pragma unroll
          for (int r = 0; r < 4; r++) {
            float pv = fexp2(StL[ct][r]);
            if (ct * 16 + quad * 4 + r > wave * 16 + l16) pv = 0.f;
            p[r] = pv;
          }
          lL += (p[0] + p[1]) + (p[2] + p[3]);
          uint2 pk = {pk_trunc(p[0], p[1]), pk_trunc(p[2], p[3])};
          *(uint2*)&PtL[l16][ct * 16 + quad * 4] = pk;
        }
      } else {
#pragma unroll
        for (int ct = 0; ct < 4; ct++) {
          float p[4];
#pragma unroll
          for (int r = 0; r < 4; r++) p[r] = fexp2(StL[ct][r]);
          lL += (p[0] + p[1]) + (p[2] + p[3]);
          uint2 pk = {pk_trunc(p[0], p[1]), pk_trunc(p[2], p[3])};
          *(uint2*)&PtL[l16][ct * 16 + quad * 4] = pk;
        }
      }
    }

    // O += P V (Pt wave-private: in-wave lgkmcnt ordering, no barrier)
    bf16x8 paH0 = *(const bf16x8*)&PtH[l16][quad * 8];
    bf16x8 paH1 = *(const bf16x8*)&PtH[l16][32 + quad * 8];
    bf16x8 paL0, paL1;
    if (doLo) {
      paL0 = *(const bf16x8*)&PtL[l16][quad * 8];
      paL1 = *(const bf16x8*)&PtL[l16][32 + quad * 8];
    }
#pragma unroll
    for (int dt = 0; dt < 4; dt++) {
      bf16x8 vb0 = *(const bf16x8*)&Vts[buf][dt * 16 + l16][quad * 8];
      bf16x8 vb1 = *(const bf16x8*)&Vts[buf][dt * 16 + l16][32 + quad * 8];
      OfrH[dt] = __builtin_amdgcn_mfma_f32_16x16x32_bf16(paH0, vb0, OfrH[dt], 0, 0, 0);
      OfrH[dt] = __builtin_amdgcn_mfma_f32_16x16x32_bf16(paH1, vb1, OfrH[dt], 0, 0, 0);
      if (doLo) {
        OfrL[dt] = __builtin_amdgcn_mfma_f32_16x16x32_bf16(paL0, vb0, OfrL[dt], 0, 0, 0);
        OfrL[dt] = __builtin_amdgcn_mfma_f32_16x16x32_bf16(paL1, vb1, OfrL[dt], 0, 0, 0);
      }
    }
    // no trailing barrier: next iter commits the OTHER buffer
  }

  // deferred cross-quad l reduction
  lL += __shfl_xor(lL, 16, 64); lL += __shfl_xor(lL, 32, 64);
  lH += __shfl_xor(lH, 16, 64); lH += __shfl_xor(lH, 32, 64);

  const int b = bh >> 4, h = bh & 15;
  float lRowL[4], lRowH[4];
#pragma unroll
  for (int r = 0; r < 4; r++) {
    lRowL[r] = __shfl(lL, quad * 4 + r, 16);
    lRowH[r] = __shfl(lH, quad * 4 + r, 16);
  }
#pragma unroll
  for (int r = 0; r < 4; r++) {
    const int qL = qBaseL + wave * 16 + quad * 4 + r;
    const int qH = qBaseH + wave * 16 + quad * 4 + r;
    const float invL = 1.0f / lRowL[r];
    const float invH = 1.0f / lRowH[r];
    unsigned short* ypL = y + ((size_t)(b * TT + qL)) * CC + h * 64 + l16;
    unsigned short* ypH = y + ((size_t)(b * TT + qH)) * CC + h * 64 + l16;
#pragma unroll
    for (int dt = 0; dt < 4; dt++) {
      ypL[dt * 16] = f2bf(OfrL[dt][r] * invL);
      ypH[dt * 16] = f2bf(OfrH[dt][r] * invH);
    }
  }
}

extern "C" void kernel_launch(void* const* d_in, const int* in_sizes, int n_in,
                              void* d_out, int out_size, void* d_ws, size_t ws_size,
                              hipStream_t stream) {
  const float* x  = (const float*)d_in[0];
  const float* Wq = (const float*)d_in[1];
  const float* bq = (const float*)d_in[2];
  const float* Wk = (const float*)d_in[3];
  const float* bk = (const float*)d_in[4];
  const float* Wv = (const float*)d_in[5];
  const float* bv = (const float*)d_in[6];
  const float* Wp = (const float*)d_in[7];
  const float* bp = (const float*)d_in[8];

  const size_t M4 = 4194304, M1 = 1048576;
  unsigned short* xb   = (unsigned short*)d_ws;  // 4M
  unsigned short* wqb  = xb + M4;                // wq,wk,wv,wp contiguous
  unsigned short* wpb  = wqb + 3 * M1;
  unsigned short* wsQ  = wpb + M1;               // [B,H,T,HD] (pre-scaled)
  unsigned short* wsK  = wsQ + M4;               // [B,H,T,HD]
  unsigned short* wsVt = wsK + M4;               // [B,H,HD,T]
  unsigned short* yb   = wsVt + M4;              // [B,T,C] bf16

  convert_all<<<4096, 256, 0, stream>>>(x, Wq, Wk, Wv, Wp, xb);
  gemm_mfma<<<dim3(32, 24), 256, 0, stream>>>(xb, wqb, bq, bk, bv,
                                              wsQ, wsK, wsVt);
  attn_mfma<<<dim3(16, BB * HH), 256, 0, stream>>>(wsQ, wsK, wsVt, yb);
  gemm_proj<<<dim3(32, 8), 512, 0, stream>>>(yb, wpb, bp, (float*)d_out);
}

// Round 7
// 183.658 us; speedup vs baseline: 1.1238x; 1.0144x over previous
//
#include <hip/hip_runtime.h>
#include <hip/hip_bf16.h>

#define BB 2
#define TT 2048
#define CC 1024
#define HH 16
#define HDD 64

typedef __attribute__((ext_vector_type(8))) short bf16x8;
typedef __attribute__((ext_vector_type(4))) float f32x4;

static __device__ __forceinline__ unsigned short f2bf(float f) {
  union { float f; unsigned u; } v; v.f = f;
  unsigned r = v.u + 0x7fffu + ((v.u >> 16) & 1u);  // RNE
  return (unsigned short)(r >> 16);
}

static __device__ __forceinline__ unsigned fbits(float f) {
  union { float f; unsigned u; } v; v.f = f; return v.u;
}

// pack two fp32 -> two bf16 (truncate) in ONE v_perm_b32
static __device__ __forceinline__ unsigned pk_trunc(float lo, float hi) {
  return __builtin_amdgcn_perm(fbits(hi), fbits(lo), 0x07060302u);
}

// raw v_exp_f32 (args bounded; skips OCML range/subnormal fixup)
static __device__ __forceinline__ float fexp2(float x) {
#if __has_builtin(__builtin_amdgcn_exp2f)
  return __builtin_amdgcn_exp2f(x);
#else
  return exp2f(x);
#endif
}

static __device__ __forceinline__ void gload_lds16(const unsigned short* g, unsigned short* l) {
  __builtin_amdgcn_global_load_lds((const __attribute__((address_space(1))) void*)g,
                                   (__attribute__((address_space(3))) void*)l, 16, 0, 0);
}

// fp32 -> bf16 for x (4M), Wq,Wk,Wv,Wp (1M each), into contiguous dst.
__global__ __launch_bounds__(256) void convert_all(
    const float* __restrict__ x, const float* __restrict__ Wq,
    const float* __restrict__ Wk, const float* __restrict__ Wv,
    const float* __restrict__ Wp, unsigned short* __restrict__ dst)
{
  const size_t M4 = 4194304, M1 = 1048576;
  const size_t e = ((size_t)blockIdx.x * 256 + threadIdx.x) * 8;
  const float* src; size_t off;
  if (e < M4)            { src = x;  off = e; }
  else if (e < M4 + M1)  { src = Wq; off = e - M4; }
  else if (e < M4 + 2*M1){ src = Wk; off = e - M4 - M1; }
  else if (e < M4 + 3*M1){ src = Wv; off = e - M4 - 2*M1; }
  else                   { src = Wp; off = e - M4 - 3*M1; }
  float4 a = *(const float4*)(src + off);
  float4 c = *(const float4*)(src + off + 4);
  unsigned short buf[8] = {f2bf(a.x), f2bf(a.y), f2bf(a.z), f2bf(a.w),
                           f2bf(c.x), f2bf(c.y), f2bf(c.z), f2bf(c.w)};
  *(uint4*)(dst + e) = *(const uint4*)buf;
}

// ---------------------------------------------------------------------------
// R17 GEMM (kept: 42.4us == 2-phase floor at K=1024; tri-buffer neutral).
// ---------------------------------------------------------------------------
__global__ __launch_bounds__(256) void gemm_mfma(
    const unsigned short* __restrict__ A, const unsigned short* __restrict__ W,
    const float* __restrict__ b0, const float* __restrict__ b1, const float* __restrict__ b2,
    unsigned short* __restrict__ oQ, unsigned short* __restrict__ oK,
    unsigned short* __restrict__ oVt)
{
  __shared__ unsigned short As[3][128][32];
  __shared__ unsigned short Bs[3][128][32];
  const int t = threadIdx.x;
  const int wv = __builtin_amdgcn_readfirstlane(t >> 6);
  const int ln = t & 63;
  const int l16 = ln & 15;
  const int quad = ln >> 4;
  const int mBase = blockIdx.x * 128;
  const int nBase = blockIdx.y * 128;
  const int wm = (wv >> 1) * 64, wn = (wv & 1) * 64;

  f32x4 acc[4][4];
#pragma unroll
  for (int i = 0; i < 4; i++)
#pragma unroll
    for (int j = 0; j < 4; j++) acc[i][j] = (f32x4){0.f, 0.f, 0.f, 0.f};

  const int rloc = t >> 2;
  const int csrc = ((t & 3) ^ ((t >> 3) & 3)) * 8;
  const unsigned short* gA = A + (size_t)(mBase + rloc) * CC + csrc;
  const unsigned short* gB = W + (size_t)(nBase + rloc) * CC + csrc;
  const int sw = (quad ^ ((l16 >> 1) & 3)) * 8;

#define STAGE(b, kt)                                                       \
  do {                                                                     \
    const size_t ko = (size_t)(kt) * 32;                                   \
    gload_lds16(gA + ko,           &As[b][0][0] + t * 8);                  \
    gload_lds16(gA + ko + 64 * CC, &As[b][64][0] + t * 8);                 \
    gload_lds16(gB + ko,           &Bs[b][0][0] + t * 8);                  \
    gload_lds16(gB + ko + 64 * CC, &Bs[b][64][0] + t * 8);                 \
  } while (0)

  STAGE(0, 0);
  STAGE(1, 1);
  int cur = 0, nxt2 = 2;
  for (int kt = 0; kt < 32; ++kt) {
    if (kt < 30) {
      STAGE(nxt2, kt + 2);
      asm volatile("s_waitcnt vmcnt(8)" ::: "memory");
    } else if (kt == 30) {
      asm volatile("s_waitcnt vmcnt(4)" ::: "memory");
    } else {
      asm volatile("s_waitcnt vmcnt(0)" ::: "memory");
    }
    __builtin_amdgcn_s_barrier();
    asm volatile("" ::: "memory");
    bf16x8 af[4], bfr[4];
#pragma unroll
    for (int i = 0; i < 4; ++i) af[i] = *(const bf16x8*)&As[cur][wm + i * 16 + l16][sw];
#pragma unroll
    for (int j = 0; j < 4; ++j) bfr[j] = *(const bf16x8*)&Bs[cur][wn + j * 16 + l16][sw];
    __builtin_amdgcn_s_setprio(1);
#pragma unroll
    for (int i = 0; i < 4; ++i)
#pragma unroll
      for (int j = 0; j < 4; ++j)
        acc[i][j] = __builtin_amdgcn_mfma_f32_16x16x32_bf16(af[i], bfr[j], acc[i][j], 0, 0, 0);
    __builtin_amdgcn_s_setprio(0);
    asm volatile("" ::: "memory");
    __builtin_amdgcn_s_barrier();
    asm volatile("" ::: "memory");
    cur = (cur == 2) ? 0 : cur + 1;
    nxt2 = (nxt2 == 2) ? 0 : nxt2 + 1;
  }
#undef STAGE

  const int which = nBase >> 10;
  const float* bias = which == 0 ? b0 : (which == 1 ? b1 : b2);
  unsigned short* dst = which == 0 ? oQ : (which == 1 ? oK : oVt);
  const float scl = which == 0 ? 0.1803368801f : 1.0f;  // 0.125*log2(e) on Q
#pragma unroll
  for (int i = 0; i < 4; i++)
#pragma unroll
    for (int r = 0; r < 4; r++) {
      const int m = mBase + wm + i * 16 + quad * 4 + r;
      const int b = m >> 11, tp = m & 2047;
#pragma unroll
      for (int j = 0; j < 4; j++) {
        const int n = nBase + wn + j * 16 + l16;
        const int nl = n & 1023, h = nl >> 6, d = nl & 63;
        const unsigned short v = f2bf((acc[i][j][r] + bias[nl]) * scl);
        if (which < 2) dst[((size_t)(b * HH + h) * TT + tp) * HDD + d] = v;
        else           dst[((size_t)(b * HH + h) * HDD + d) * TT + tp] = v;
      }
    }
}

// Output projection (R17, kept).
__global__ __launch_bounds__(512) void gemm_proj(
    const unsigned short* __restrict__ A, const unsigned short* __restrict__ W,
    const float* __restrict__ bias, float* __restrict__ out)
{
  __shared__ unsigned short As[3][128][32];
  __shared__ unsigned short Bs[3][128][32];
  const int t = threadIdx.x;
  const int wv = __builtin_amdgcn_readfirstlane(t >> 6);  // 0..7
  const int ln = t & 63;
  const int l16 = ln & 15;
  const int quad = ln >> 4;
  const int mBase = blockIdx.x * 128;
  const int nBase = blockIdx.y * 128;
  const int wm = (wv >> 2) * 64;        // {0,64}
  const int wn = (wv & 3) * 32;         // {0,32,64,96}

  f32x4 acc[4][2];
#pragma unroll
  for (int i = 0; i < 4; i++)
#pragma unroll
    for (int j = 0; j < 2; j++) acc[i][j] = (f32x4){0.f, 0.f, 0.f, 0.f};

  const int rloc = t >> 2;                               // 0..127
  const int csrc = ((t & 3) ^ ((t >> 3) & 3)) * 8;
  const unsigned short* gA = A + (size_t)(mBase + rloc) * CC + csrc;
  const unsigned short* gB = W + (size_t)(nBase + rloc) * CC + csrc;
  const int sw = (quad ^ ((l16 >> 1) & 3)) * 8;

#define STAGE(b, kt)                                                       \
  do {                                                                     \
    const size_t ko = (size_t)(kt) * 32;                                   \
    gload_lds16(gA + ko, &As[b][0][0] + t * 8);                            \
    gload_lds16(gB + ko, &Bs[b][0][0] + t * 8);                            \
  } while (0)

  STAGE(0, 0);
  STAGE(1, 1);
  int cur = 0, nxt2 = 2;
  for (int kt = 0; kt < 32; ++kt) {
    if (kt < 30) {
      STAGE(nxt2, kt + 2);
      asm volatile("s_waitcnt vmcnt(4)" ::: "memory");
    } else if (kt == 30) {
      asm volatile("s_waitcnt vmcnt(2)" ::: "memory");
    } else {
      asm volatile("s_waitcnt vmcnt(0)" ::: "memory");
    }
    __builtin_amdgcn_s_barrier();
    asm volatile("" ::: "memory");
    bf16x8 af[4], bfr[2];
#pragma unroll
    for (int i = 0; i < 4; ++i) af[i] = *(const bf16x8*)&As[cur][wm + i * 16 + l16][sw];
#pragma unroll
    for (int j = 0; j < 2; ++j) bfr[j] = *(const bf16x8*)&Bs[cur][wn + j * 16 + l16][sw];
    __builtin_amdgcn_s_setprio(1);
#pragma unroll
    for (int i = 0; i < 4; ++i)
#pragma unroll
      for (int j = 0; j < 2; ++j)
        acc[i][j] = __builtin_amdgcn_mfma_f32_16x16x32_bf16(af[i], bfr[j], acc[i][j], 0, 0, 0);
    __builtin_amdgcn_s_setprio(0);
    asm volatile("" ::: "memory");
    __builtin_amdgcn_s_barrier();
    asm volatile("" ::: "memory");
    cur = (cur == 2) ? 0 : cur + 1;
    nxt2 = (nxt2 == 2) ? 0 : nxt2 + 1;
  }
#undef STAGE

#pragma unroll
  for (int i = 0; i < 4; i++)
#pragma unroll
    for (int r = 0; r < 4; r++) {
      const int m = mBase + wm + i * 16 + quad * 4 + r;
#pragma unroll
      for (int j = 0; j < 2; j++) {
        const int n = nBase + wn + j * 16 + l16;
        out[(size_t)m * CC + n] = acc[i][j][r] + bias[n];
      }
    }
}

// ---------------------------------------------------------------------------
// R18 attn: 8-wave tile-split (waves 0-3 = lo tile, 4-7 = hi tile).
// Theory: R7 structure is latency-bound (Pt LDS round-trip, MFMA->exp,
// exp->pack chains) at only 2 waves/SIMD (2 blocks/CU x 4 waves). Splitting
// the pair across 8 waves halves per-wave state (~100 VGPR < 128) so
// __launch_bounds__(512,4) gives 16 waves/CU = 4 waves/SIMD: 2x TLP, same
// total work/arithmetic/memory pattern. Q now loaded DIRECTLY global->regs
// (4 coalesced 16B loads/lane; QP staging + prologue barrier removed).
// Pt = per-wave 16-row slot in a [128][72] buffer (same bank-optimal pad).
// Idle lo-waves (kt>qtL) still stage K/V + hit the barrier: dbuf invariant
// identical to R7's verified single-barrier scheme.
// ---------------------------------------------------------------------------
__global__ __launch_bounds__(512, 4) void attn_mfma(
    const unsigned short* __restrict__ Q, const unsigned short* __restrict__ K,
    const unsigned short* __restrict__ Vt, unsigned short* __restrict__ y)
{
  __shared__ unsigned short Pt[128][72];     // 8 waves x 16-row P^T slots
  __shared__ unsigned short Ks[2][64][72];
  __shared__ unsigned short Vts[2][64][72];

  const int t = threadIdx.x;
  const int a = blockIdx.x;        // 0..15
  const int bh = blockIdx.y;       // 0..31
  const int wave = t >> 6;         // 0..7
  const int lane = t & 63;
  const int l16 = lane & 15;
  const int quad = lane >> 4;

  const size_t base = (size_t)bh * TT * HDD;
  const int qtL = a, qtH = 31 - a;
  const bool isHi = wave >= 4;
  const int myQt = isHi ? qtH : qtL;
  const int myQBase = (isHi ? qtH : qtL) * 64;
  const int rowInTile = (wave & 3) * 16 + l16;   // this lane's q-row (0..63)

  // Q fragments: direct global->reg, coalesced (2KB contiguous per wave)
  const unsigned short* qrow = Q + base + (size_t)(myQBase + rowInTile) * HDD + quad * 8;
  bf16x8 qf0 = *(const bf16x8*)(qrow);
  bf16x8 qf1 = *(const bf16x8*)(qrow + 32);

  unsigned short (*Ptw)[72] = (unsigned short (*)[72])&Pt[wave * 16];

  // K/V staging map: 512 threads, 1 uint4 each for K and V per tile
  const int sr = t >> 3, sc = (t & 7) * 8;       // row 0..63, col-chunk
  const unsigned short* kbase = K + base + (size_t)sr * HDD + sc;
  const unsigned short* vbase = Vt + base + (size_t)sr * TT + sc;
  uint4 kr = *(const uint4*)(kbase);
  uint4 vr = *(const uint4*)(vbase);

  float lsum = 0.f;
  f32x4 Ofr[4];
#pragma unroll
  for (int dt = 0; dt < 4; dt++) Ofr[dt] = (f32x4){0.f, 0.f, 0.f, 0.f};

  for (int kt = 0; kt <= qtH; kt++) {
    const int buf = kt & 1;
    *(uint4*)&Ks[buf][sr][sc]  = kr;
    *(uint4*)&Vts[buf][sr][sc] = vr;
    __syncthreads();  // ONLY barrier: commits visible; prior-buf readers done
    if (kt < qtH) {
      kr = *(const uint4*)(kbase + (size_t)(kt + 1) * 64 * HDD);
      vr = *(const uint4*)(vbase + (kt + 1) * 64);
    }
    if (kt <= myQt) {
      // S^T = K Q^T for this wave's tile
      f32x4 St[4];
#pragma unroll
      for (int ct = 0; ct < 4; ct++) {
        bf16x8 a0 = *(const bf16x8*)&Ks[buf][ct * 16 + l16][quad * 8];
        bf16x8 a1 = *(const bf16x8*)&Ks[buf][ct * 16 + l16][32 + quad * 8];
        f32x4 s = (f32x4){0.f, 0.f, 0.f, 0.f};
        s = __builtin_amdgcn_mfma_f32_16x16x32_bf16(a0, qf0, s, 0, 0, 0);
        s = __builtin_amdgcn_mfma_f32_16x16x32_bf16(a1, qf1, s, 0, 0, 0);
        St[ct] = s;
      }
      // softmax (mask only on the diagonal iteration — wave-uniform branch)
      if (kt == myQt) {
#pragma unroll
        for (int ct = 0; ct < 4; ct++) {
          float p[4];
#pragma unroll
          for (int r = 0; r < 4; r++) {
            float pv = fexp2(St[ct][r]);
            if (ct * 16 + quad * 4 + r > rowInTile) pv = 0.f;
            p[r] = pv;
          }
          lsum += (p[0] + p[1]) + (p[2] + p[3]);
          uint2 pk = {pk_trunc(p[0], p[1]), pk_trunc(p[2], p[3])};
          *(uint2*)&Ptw[l16][ct * 16 + quad * 4] = pk;
        }
      } else {
#pragma unroll
        for (int ct = 0; ct < 4; ct++) {
          float p[4];
#pragma unroll
          for (int r = 0; r < 4; r++) p[r] = fexp2(St[ct][r]);
          lsum += (p[0] + p[1]) + (p[2] + p[3]);
          uint2 pk = {pk_trunc(p[0], p[1]), pk_trunc(p[2], p[3])};
          *(uint2*)&Ptw[l16][ct * 16 + quad * 4] = pk;
        }
      }
      // O += P V (Ptw wave-private: in-wave lgkmcnt ordering, no barrier)
      bf16x8 pa0 = *(const bf16x8*)&Ptw[l16][quad * 8];
      bf16x8 pa1 = *(const bf16x8*)&Ptw[l16][32 + quad * 8];
#pragma unroll
      for (int dt = 0; dt < 4; dt++) {
        bf16x8 vb0 = *(const bf16x8*)&Vts[buf][dt * 16 + l16][quad * 8];
        bf16x8 vb1 = *(const bf16x8*)&Vts[buf][dt * 16 + l16][32 + quad * 8];
        Ofr[dt] = __builtin_amdgcn_mfma_f32_16x16x32_bf16(pa0, vb0, Ofr[dt], 0, 0, 0);
        Ofr[dt] = __builtin_amdgcn_mfma_f32_16x16x32_bf16(pa1, vb1, Ofr[dt], 0, 0, 0);
      }
    }
    // no trailing barrier: next iter commits the OTHER buffer
  }

  // deferred cross-quad l reduction
  lsum += __shfl_xor(lsum, 16, 64);
  lsum += __shfl_xor(lsum, 32, 64);

  const int b = bh >> 4, h = bh & 15;
  float lRow[4];
#pragma unroll
  for (int r = 0; r < 4; r++) lRow[r] = __shfl(lsum, quad * 4 + r, 16);
#pragma unroll
  for (int r = 0; r < 4; r++) {
    const int q = myQBase + (wave & 3) * 16 + quad * 4 + r;
    const float inv = 1.0f / lRow[r];
    unsigned short* yp = y + ((size_t)(b * TT + q)) * CC + h * 64 + l16;
#pragma unroll
    for (int dt = 0; dt < 4; dt++) yp[dt * 16] = f2bf(Ofr[dt][r] * inv);
  }
}

extern "C" void kernel_launch(void* const* d_in, const int* in_sizes, int n_in,
                              void* d_out, int out_size, void* d_ws, size_t ws_size,
                              hipStream_t stream) {
  const float* x  = (const float*)d_in[0];
  const float* Wq = (const float*)d_in[1];
  const float* bq = (const float*)d_in[2];
  const float* Wk = (const float*)d_in[3];
  const float* bk = (const float*)d_in[4];
  const float* Wv = (const float*)d_in[5];
  const float* bv = (const float*)d_in[6];
  const float* Wp = (const float*)d_in[7];
  const float* bp = (const float*)d_in[8];

  const size_t M4 = 4194304, M1 = 1048576;
  unsigned short* xb   = (unsigned short*)d_ws;  // 4M
  unsigned short* wqb  = xb + M4;                // wq,wk,wv,wp contiguous
  unsigned short* wpb  = wqb + 3 * M1;
  unsigned short* wsQ  = wpb + M1;               // [B,H,T,HD] (pre-scaled)
  unsigned short* wsK  = wsQ + M4;               // [B,H,T,HD]
  unsigned short* wsVt = wsK + M4;               // [B,H,HD,T]
  unsigned short* yb   = wsVt + M4;              // [B,T,C] bf16

  convert_all<<<4096, 256, 0, stream>>>(x, Wq, Wk, Wv, Wp, xb);
  gemm_mfma<<<dim3(32, 24), 256, 0, stream>>>(xb, wqb, bq, bk, bv,
                                              wsQ, wsK, wsVt);
  attn_mfma<<<dim3(16, BB * HH), 512, 0, stream>>>(wsQ, wsK, wsVt, yb);
  gemm_proj<<<dim3(32, 8), 512, 0, stream>>>(yb, wpb, bp, (float*)d_out);
}